// Round 6
// baseline (9665.582 us; speedup 1.0000x reference)
//
#include <hip/hip_runtime.h>
#include <stdint.h>
#include <string.h>

#define NBATCH 8
#define NSPK_  4
#define DIMS   512
#define TLEN   2000
#define KC     4
#define NPTS   8000            // points per batch
#define NBLK   1000            // Lloyd / dist / prep grid
#define NTHR   256
#define PPB    64              // points per block
#define BPB    125             // blocks per batch
#define MAXIT  100

#define THREEFRY_PARTITIONABLE 1

struct RArg { float r[3][NBATCH]; };

// ---- exact replica of numpy pairwise_sum (umath loops), stride in elements ----
__device__ float np_pw(const float* a, int n, int st){
  #pragma clang fp contract(off)
  if (n < 8){
    float r = 0.f;
    for (int i = 0; i < n; ++i) r += a[(long)i*st];
    return r;
  }
  if (n <= 128){
    float r0=a[0], r1=a[st], r2=a[2*st], r3=a[3*st],
          r4=a[4*st], r5=a[5*st], r6=a[6*st], r7=a[7*st];
    int i = 8;
    for (; i < n - (n & 7); i += 8){
      r0 += a[(long)(i+0)*st]; r1 += a[(long)(i+1)*st];
      r2 += a[(long)(i+2)*st]; r3 += a[(long)(i+3)*st];
      r4 += a[(long)(i+4)*st]; r5 += a[(long)(i+5)*st];
      r6 += a[(long)(i+6)*st]; r7 += a[(long)(i+7)*st];
    }
    float res = ((r0 + r1) + (r2 + r3)) + ((r4 + r5) + (r6 + r7));
    for (; i < n; ++i) res += a[(long)i*st];
    return res;
  }
  int n2 = n/2; n2 -= (n2 & 7);
  return np_pw(a, n2, st) + np_pw(a + (long)n2*st, n - n2, st);
}
__device__ float np_pw_sq(const float* a, int n, int st){
  #pragma clang fp contract(off)
  if (n < 8){
    float r = 0.f;
    for (int i = 0; i < n; ++i){ float x = a[(long)i*st]; float s = x*x; r += s; }
    return r;
  }
  if (n <= 128){
    float x0=a[0],x1=a[st],x2=a[2*st],x3=a[3*st],
          x4=a[4*st],x5=a[5*st],x6=a[6*st],x7=a[7*st];
    float r0=x0*x0, r1=x1*x1, r2=x2*x2, r3=x3*x3,
          r4=x4*x4, r5=x5*x5, r6=x6*x6, r7=x7*x7;
    int i = 8;
    for (; i < n - (n & 7); i += 8){
      float y0=a[(long)(i+0)*st], y1=a[(long)(i+1)*st], y2=a[(long)(i+2)*st], y3=a[(long)(i+3)*st];
      float y4=a[(long)(i+4)*st], y5=a[(long)(i+5)*st], y6=a[(long)(i+6)*st], y7=a[(long)(i+7)*st];
      r0 += y0*y0; r1 += y1*y1; r2 += y2*y2; r3 += y3*y3;
      r4 += y4*y4; r5 += y5*y5; r6 += y6*y6; r7 += y7*y7;
    }
    float res = ((r0 + r1) + (r2 + r3)) + ((r4 + r5) + (r6 + r7));
    for (; i < n; ++i){ float x = a[(long)i*st]; float s = x*x; res += s; }
    return res;
  }
  int n2 = n/2; n2 -= (n2 & 7);
  return np_pw_sq(a, n2, st) + np_pw_sq(a + (long)n2*st, n - n2, st);
}

// ======== phase 0: fsq via 4-leaf parallel np tree; center row 0; rows 1..3 = 0
__global__ __launch_bounds__(NTHR)
void k_prep(const float* __restrict__ X, float* __restrict__ C, float* __restrict__ fsq){
  const int blk = blockIdx.x, tid = threadIdx.x;
  const int q = tid >> 6, l = tid & 63;    // wave = quarter, lane = point
  __shared__ float red[4][64];

  const int P = blk*64 + l;                // 1000*64 = 64000 points
  const int bf = P / NPTS, gf = P - bf*NPTS;
  const int nf = gf / TLEN, tf = gf - nf*TLEN;
  red[q][l] = np_pw_sq(X + ((size_t)(bf*NSPK_ + nf)*DIMS + q*128)*TLEN + tf, 128, TLEN);
  __syncthreads();
  if (tid < 64)
    fsq[blk*64 + tid] = (red[0][tid] + red[1][tid]) + (red[2][tid] + red[3][tid]);

  if (blk < NBATCH){
    for (int d = tid; d < DIMS; d += NTHR)
      C[blk*KC*DIMS + d] = X[((size_t)(blk*NSPK_)*DIMS + d)*TLEN];
  } else if (blk < 2*NBATCH){
    int bb = blk - NBATCH;
    for (int e = tid; e < 3*DIMS; e += NTHR) C[bb*KC*DIMS + DIMS + e] = 0.f;
  }
}

// ======== init dist: dmin over all 4 rows (zero rows give fsq == reference :i+1 slice)
__global__ __launch_bounds__(NTHR)
void k_dist(const float* __restrict__ X, const float* __restrict__ C,
            const float* __restrict__ fsq, float* __restrict__ dmin){
  const int blk = blockIdx.x, tid = threadIdx.x;
  const int w = tid >> 6, l = tid & 63;
  const int b = blk / BPB;
  const int P = blk*PPB + l;
  const int g = P - b*NPTS;
  const int n = g / TLEN, t = g - n*TLEN;

  __shared__ __align__(16) float cent[DIMS*KC];
  __shared__ float red[4][KC][PPB];
  __shared__ float csq_s[KC];

  const float* Cb = C + b*KC*DIMS;
  #pragma unroll
  for (int j = 0; j < 8; ++j){
    int e = tid*8 + j;
    cent[e] = Cb[(e&3)*DIMS + (e>>2)];
  }
  { const float* ck = Cb + w*DIMS + l*8;
    float s = 0.f;
    #pragma unroll
    for (int j = 0; j < 8; ++j){ float c = ck[j]; s += c*c; }
    #pragma unroll
    for (int o = 32; o; o >>= 1) s += __shfl_xor(s, o, 64);
    if (l == 0) csq_s[w] = s;
  }
  __syncthreads();

  const float* xp = X + (((size_t)(b*NSPK_ + n)*DIMS) + w*128)*TLEN + t;
  const float4* c4p = (const float4*)cent + w*128;
  float a0=0,a1=0,a2=0,a3=0;
  #pragma unroll 8
  for (int dq = 0; dq < 128; ++dq){
    float x = xp[(size_t)dq*TLEN];
    float4 c = c4p[dq];
    a0 += x*c.x; a1 += x*c.y; a2 += x*c.z; a3 += x*c.w;
  }
  red[w][0][l]=a0; red[w][1][l]=a1; red[w][2][l]=a2; red[w][3][l]=a3;
  __syncthreads();
  if (tid < PPB){
    float A0 = red[0][0][l]+red[1][0][l]+red[2][0][l]+red[3][0][l];
    float A1 = red[0][1][l]+red[1][1][l]+red[2][1][l]+red[3][1][l];
    float A2 = red[0][2][l]+red[1][2][l]+red[2][2][l]+red[3][2][l];
    float A3 = red[0][3][l]+red[1][3][l]+red[2][3][l]+red[3][3][l];
    float fs = fsq[P];
    float dm = (fs + csq_s[0]) - 2.f*A0;
    dm = fminf(dm, (fs + csq_s[1]) - 2.f*A1);
    dm = fminf(dm, (fs + csq_s[2]) - 2.f*A2);
    dm = fminf(dm, (fs + csq_s[3]) - 2.f*A3);
    dmin[P] = dm;
  }
}

// ======== selection (np-exact): grid 8, one block per batch; writes center row i
__global__ __launch_bounds__(NTHR)
void k_select(const float* __restrict__ X, float* __restrict__ C,
              const float* __restrict__ dmin, RArg ra, int i){
  const int bs = blockIdx.x, tid = threadIdx.x;
  const int w = tid >> 6, l = tid & 63;
  __shared__ __align__(16) float sbuf[NPTS];   // 32 KB
  __shared__ __align__(16) float pbuf[NPTS];   // 32 KB
  __shared__ float fsh[1];
  __shared__ int   ired[4];
  float rT = ra.r[i-1][bs];

  for (int e = tid; e < NPTS; e += NTHR) sbuf[e] = dmin[bs*NPTS + e];
  __syncthreads();
  if (w == 0){
    const int chunk = l >> 3, idx = l & 7;
    const int offs[8] = {0,120,248,368,496,616,744,872};
    int off = chunk*1000 + offs[idx];
    int len = (idx==0 || idx==2 || idx==4) ? 120 : 128;
    float v = np_pw(sbuf + off, len, 1);
    #pragma unroll
    for (int o = 1; o < 64; o <<= 1) v = v + __shfl_xor(v, o, 64);
    if (l == 0) fsh[0] = v;
  }
  __syncthreads();
  float tot = fsh[0];
  for (int e = tid; e < NPTS; e += NTHR) sbuf[e] = sbuf[e] / tot;  // IEEE div like np
  __syncthreads();
  if (tid == 0){
    #pragma clang fp contract(off)
    float b0[32], b1[32];
    #pragma unroll
    for (int u = 0; u < 32; ++u) b0[u] = sbuf[u];
    float run = 0.f;
    for (int j = 0; j < NPTS; j += 64){
      #pragma unroll
      for (int u = 0; u < 32; ++u) b1[u] = sbuf[j + 32 + u];
      #pragma unroll
      for (int u = 0; u < 32; ++u){ run = run + b0[u]; pbuf[j + u] = run; }
      if (j + 64 < NPTS){
        #pragma unroll
        for (int u = 0; u < 32; ++u) b0[u] = sbuf[j + 64 + u];
      }
      #pragma unroll
      for (int u = 0; u < 32; ++u){ run = run + b1[u]; pbuf[j + 32 + u] = run; }
    }
  }
  __syncthreads();
  int cnt = 0;
  for (int e = tid; e < NPTS; e += NTHR) cnt += (pbuf[e] <= rT) ? 1 : 0;
  #pragma unroll
  for (int o = 32; o; o >>= 1) cnt += __shfl_xor(cnt, o, 64);
  if (l == 0) ired[w] = cnt;
  __syncthreads();
  int sel = (ired[0] + ired[1] + ired[2] + ired[3]) - 1;
  for (int d = tid; d < DIMS; d += NTHR){
    float v = 0.f;
    if (sel >= 0){
      int ns = sel / TLEN, ts = sel - ns*TLEN;
      v = X[((size_t)(bs*NSPK_ + ns)*DIMS + d)*TLEN + ts];
    }
    C[(bs*KC + i)*DIMS + d] = v;
  }
}

// reduce-scatter pair step: lane with bitset keeps hi (higher index), sends lo.
#define RSTEP(lo_v, hi_v, off, bitset, dst) do {            \
    float snd_ = (bitset) ? (lo_v) : (hi_v);                \
    float kp_  = (bitset) ? (hi_v) : (lo_v);                \
    dst = kp_ + __shfl_xor(snd_, off, 64); } while (0)

// ======== Lloyd iteration v2: BARRIER-FREE main loop.
// Each wave owns 16 points (4 per round x 4 rounds); lane l covers d-rows
// {dd*64+l}, so the full-d dot reduce is one in-wave 64-lane xor tree.
// Round h, wave w reads t-chunk g0+h*16+w*4: the block's 4 waves tile one
// 64-B sector per row per round (MSHR-merge friendly).
// Cluster sums accumulate in registers (0/1-mask FMAs); per-wave partials go
// to part[blk][w][d] (float4 over k); k_reduce folds the extra factor 4.
__global__ __launch_bounds__(NTHR, 4)
void k_iter(const float* __restrict__ X, const float* __restrict__ C,
            const float* __restrict__ fsq, float* __restrict__ part,
            int* __restrict__ pnum){
  const int blk = blockIdx.x, tid = threadIdx.x;
  const int w = tid >> 6, l = tid & 63;
  const int jq = (l >> 2) & 3;            // point-in-round for this lane
  const int kq = l & 3;                   // cluster index for this lane
  const int b = blk / BPB;
  const int g0 = (blk - b*BPB)*PPB;

  __shared__ __align__(16) float4 cent[DIMS];   // cent[d] = {C[0..3][d]}, 8 KB
  __shared__ float csq_s[KC];
  __shared__ int   cntw[4][KC];

  const float* Cb = C + b*KC*DIMS;
  for (int e = tid; e < DIMS; e += NTHR){
    float4 cv;
    cv.x = Cb[e]; cv.y = Cb[DIMS+e]; cv.z = Cb[2*DIMS+e]; cv.w = Cb[3*DIMS+e];
    cent[e] = cv;
  }
  // csq (identical summation order to previous kernel: wave w -> cluster w)
  { const float* ck = Cb + w*DIMS + l*8;
    float s = 0.f;
    #pragma unroll
    for (int j = 0; j < 8; ++j){ float c = ck[j]; s += c*c; }
    #pragma unroll
    for (int o = 32; o; o >>= 1) s += __shfl_xor(s, o, 64);
    if (l == 0) csq_s[w] = s * (1.f/512.f);
  }
  __syncthreads();                        // the ONLY pre-loop barrier
  const float csq_l = csq_s[kq];

  // fsq for this lane's point in each round
  float fq[4];
  #pragma unroll
  for (int h = 0; h < 4; ++h)
    fq[h] = fsq[b*NPTS + g0 + h*16 + w*4 + jq];

  float4 acc[8];
  #pragma unroll
  for (int dd = 0; dd < 8; ++dd) acc[dd] = make_float4(0.f,0.f,0.f,0.f);
  int c0=0, c1=0, c2=0, c3=0;

  const bool hb0 = l & 1, hb1 = l & 2, hb2 = l & 4, hb3 = l & 8;

  #pragma unroll
  for (int h = 0; h < 4; ++h){
    const int gp = g0 + h*16 + w*4;       // quad of t never straddles n (4|2000)
    const int n = gp / TLEN, t = gp - n*TLEN;
    const float* xr = X + ((size_t)(b*NSPK_ + n)*DIMS + l)*TLEN + t;
    float4 x4[8];
    float4 a0 = {0,0,0,0}, a1 = {0,0,0,0}, a2 = {0,0,0,0}, a3 = {0,0,0,0};
    #pragma unroll
    for (int dd = 0; dd < 8; ++dd){
      x4[dd] = *(const float4*)(xr + (size_t)dd*64*TLEN);
      float4 c = cent[dd*64 + l];
      a0.x += x4[dd].x*c.x; a0.y += x4[dd].x*c.y; a0.z += x4[dd].x*c.z; a0.w += x4[dd].x*c.w;
      a1.x += x4[dd].y*c.x; a1.y += x4[dd].y*c.y; a1.z += x4[dd].y*c.z; a1.w += x4[dd].y*c.w;
      a2.x += x4[dd].z*c.x; a2.y += x4[dd].z*c.y; a2.z += x4[dd].z*c.z; a2.w += x4[dd].z*c.w;
      a3.x += x4[dd].w*c.x; a3.y += x4[dd].w*c.y; a3.z += x4[dd].w*c.z; a3.w += x4[dd].w*c.w;
    }
    // 64-lane reduce-scatter of 16 values; lane l ends with (j,k)=(jq,kq).
    // stage xor1: k-bit0
    float t0,t1,t2,t3,t4,t5,t6,t7;
    RSTEP(a0.x, a0.y, 1, hb0, t0);  RSTEP(a0.z, a0.w, 1, hb0, t1);
    RSTEP(a1.x, a1.y, 1, hb0, t2);  RSTEP(a1.z, a1.w, 1, hb0, t3);
    RSTEP(a2.x, a2.y, 1, hb0, t4);  RSTEP(a2.z, a2.w, 1, hb0, t5);
    RSTEP(a3.x, a3.y, 1, hb0, t6);  RSTEP(a3.z, a3.w, 1, hb0, t7);
    // stage xor2: k-bit1
    float u0,u1,u2,u3;
    RSTEP(t0, t1, 2, hb1, u0);  RSTEP(t2, t3, 2, hb1, u1);
    RSTEP(t4, t5, 2, hb1, u2);  RSTEP(t6, t7, 2, hb1, u3);
    // stage xor4: j-bit0
    float v0, v1;
    RSTEP(u0, u1, 4, hb2, v0);  RSTEP(u2, u3, 4, hb2, v1);
    // stage xor8: j-bit1
    float rr;
    RSTEP(v0, v1, 8, hb3, rr);
    // all-reduce the 4 16-lane-group partials (replicas are bit-identical)
    rr += __shfl_xor(rr, 16, 64);
    rr += __shfl_xor(rr, 32, 64);

    // distance for (point jq, cluster kq), then first-min argmin within quad
    float e = (fq[h]*(1.f/512.f) + csq_l) - 2.f*(rr*(1.f/512.f));
    int ki = kq;
    { float ov = __shfl_xor(e, 1, 64); int oi = __shfl_xor(ki, 1, 64);
      bool tk = (ov < e) || (ov == e && oi < ki);
      e = tk ? ov : e; ki = tk ? oi : ki; }
    { float ov = __shfl_xor(e, 2, 64); int oi = __shfl_xor(ki, 2, 64);
      bool tk = (ov < e) || (ov == e && oi < ki);
      e = tk ? ov : e; ki = tk ? oi : ki; }
    // gather the wave's 4 assignments into one wave-uniform packed word
    int p = ki << (2*jq);
    p |= __shfl_xor(p, 4, 64);
    p |= __shfl_xor(p, 8, 64);

    c0 += ((p&3)==0) + (((p>>2)&3)==0) + (((p>>4)&3)==0) + (((p>>6)&3)==0);
    c1 += ((p&3)==1) + (((p>>2)&3)==1) + (((p>>4)&3)==1) + (((p>>6)&3)==1);
    c2 += ((p&3)==2) + (((p>>2)&3)==2) + (((p>>4)&3)==2) + (((p>>6)&3)==2);
    c3 += ((p&3)==3) + (((p>>2)&3)==3) + (((p>>4)&3)==3) + (((p>>6)&3)==3);

    // cluster sums: 0/1-mask FMAs, no divergence, no LDS
    #pragma unroll
    for (int j = 0; j < 4; ++j){
      int kj = (p >> (2*j)) & 3;
      float f0 = (kj==0) ? 1.f : 0.f, f1 = (kj==1) ? 1.f : 0.f;
      float f2 = (kj==2) ? 1.f : 0.f, f3 = (kj==3) ? 1.f : 0.f;
      #pragma unroll
      for (int dd = 0; dd < 8; ++dd){
        float xv = (j==0) ? x4[dd].x : (j==1) ? x4[dd].y : (j==2) ? x4[dd].z : x4[dd].w;
        acc[dd].x += xv*f0; acc[dd].y += xv*f1; acc[dd].z += xv*f2; acc[dd].w += xv*f3;
      }
    }
  }

  // epilogue: per-wave partials straight to global; one barrier for pnum only
  if (l == 0){ cntw[w][0]=c0; cntw[w][1]=c1; cntw[w][2]=c2; cntw[w][3]=c3; }
  float4* pw = (float4*)part + ((size_t)blk*4 + w)*DIMS;
  #pragma unroll
  for (int dd = 0; dd < 8; ++dd) pw[dd*64 + l] = acc[dd];
  __syncthreads();
  if (tid < KC)
    pnum[blk*4 + tid] = cntw[0][tid] + cntw[1][tid] + cntw[2][tid] + cntw[3][tid];
}

// ======== reduce partials -> centers. grid 64: blk = bb*8 + seg(64 d's)
// part is [blk][w][d] float4 (k in components); sums j ascending, w inner.
__global__ __launch_bounds__(NTHR)
void k_reduce(const float* __restrict__ part, const int* __restrict__ pnum,
              float* __restrict__ C){
  const int blk = blockIdx.x, tid = threadIdx.x;
  const int seg = blk & 7, bb = blk >> 3;
  const int w = tid >> 6, l = tid & 63;
  __shared__ __align__(16) float4 red[4][64];
  __shared__ int4 nsw[4];

  int4 v = {0,0,0,0};
  if (tid < BPB) v = *(const int4*)&pnum[(bb*BPB + tid)*4];
  #pragma unroll
  for (int o = 32; o; o >>= 1){
    v.x += __shfl_xor(v.x, o, 64); v.y += __shfl_xor(v.y, o, 64);
    v.z += __shfl_xor(v.z, o, 64); v.w += __shfl_xor(v.w, o, 64);
  }
  if (l == 0) nsw[w] = v;

  int jb = (BPB*w) >> 2, je = (BPB*(w+1)) >> 2;   // fixed quarters of 125
  float4 s = {0,0,0,0};
  const float4* pp = (const float4*)part;
  for (int j = jb; j < je; ++j){
    #pragma unroll
    for (int ww = 0; ww < 4; ++ww){
      float4 t = pp[((size_t)(bb*BPB + j)*4 + ww)*DIMS + seg*64 + l];
      s.x += t.x; s.y += t.y; s.z += t.z; s.w += t.w;
    }
  }
  red[w][l] = s;
  __syncthreads();
  if (tid < 64){
    float4 r0 = red[0][l], r1 = red[1][l], r2 = red[2][l], r3 = red[3][l];
    float tsx = r0.x + r1.x + r2.x + r3.x;
    float tsy = r0.y + r1.y + r2.y + r3.y;
    float tsz = r0.z + r1.z + r2.z + r3.z;
    float tsw = r0.w + r1.w + r2.w + r3.w;
    int4 n0 = nsw[0], n1 = nsw[1], n2 = nsw[2], n3 = nsw[3];
    float dx = (float)(n0.x+n1.x+n2.x+n3.x) + 1e-8f;
    float dy = (float)(n0.y+n1.y+n2.y+n3.y) + 1e-8f;
    float dz = (float)(n0.z+n1.z+n2.z+n3.z) + 1e-8f;
    float dw = (float)(n0.w+n1.w+n2.w+n3.w) + 1e-8f;
    float* Cp = C + bb*KC*DIMS + seg*64 + l;
    Cp[0]        = tsx / dx;
    Cp[DIMS]     = tsy / dy;
    Cp[2*DIMS]   = tsz / dz;
    Cp[3*DIMS]   = tsw / dw;
  }
}

// ======================= host: threefry2x32 (JAX-compatible) =======================
static inline uint32_t rotl_(uint32_t x, int r){ return (x << r) | (x >> (32 - r)); }
static void tf2x32(uint32_t k0, uint32_t k1, uint32_t x0, uint32_t x1,
                   uint32_t* o0, uint32_t* o1){
  static const int R0[4] = {13,15,26,6}, R1[4] = {17,29,16,24};
  uint32_t ks[3] = { k0, k1, k0 ^ k1 ^ 0x1BD11BDAu };
  x0 += ks[0]; x1 += ks[1];
  for (int g = 0; g < 5; ++g){
    const int* rot = (g & 1) ? R1 : R0;
    for (int r = 0; r < 4; ++r){ x0 += x1; x1 = rotl_(x1, rot[r]); x1 ^= x0; }
    x0 += ks[(g+1)%3];
    x1 += ks[(g+2)%3] + (uint32_t)(g+1);
  }
  *o0 = x0; *o1 = x1;
}
static float tf_uniform_bits(uint32_t bits){
  uint32_t u = (bits >> 9) | 0x3f800000u;
  float f; memcpy(&f, &u, 4);
  return f - 1.0f;
}

extern "C" void kernel_launch(void* const* d_in, const int* in_sizes, int n_in,
                              void* d_out, int out_size, void* d_ws, size_t ws_size,
                              hipStream_t stream) {
  (void)in_sizes; (void)n_in; (void)out_size; (void)ws_size;
  const float* X = (const float*)d_in[0];
  float* centers = (float*)d_out;                 // (8,4,512)

  char* w = (char*)d_ws;
  float* fsq  = (float*)w;  w += (size_t)NBATCH*NPTS*4;            // 256 KB
  float* dmin = (float*)w;  w += (size_t)NBATCH*NPTS*4;            // 256 KB
  float* part = (float*)w;  w += (size_t)NBLK*4*DIMS*16;           // 32.8 MB (per-wave float4)
  int*   pnum = (int*)w;    w += (size_t)NBLK*KC*4;                // 16 KB

  RArg ra;
  uint32_t k0 = 0u, k1 = 1u;
  for (int i = 0; i < 3; ++i){
#if THREEFRY_PARTITIONABLE
    uint32_t nk0, nk1, s0, s1;
    tf2x32(k0, k1, 0u, 0u, &nk0, &nk1);
    tf2x32(k0, k1, 0u, 1u, &s0, &s1);
    k0 = nk0; k1 = nk1;
    for (int bq = 0; bq < NBATCH; ++bq){
      uint32_t b1v, b2v; tf2x32(s0, s1, 0u, (uint32_t)bq, &b1v, &b2v);
      ra.r[i][bq] = tf_uniform_bits(b1v ^ b2v);
    }
#else
    uint32_t a0, b0, a1, b1;
    tf2x32(k0, k1, 0u, 2u, &a0, &b0);
    tf2x32(k0, k1, 1u, 3u, &a1, &b1);
    uint32_t s0 = b0, s1 = b1;
    k0 = a0; k1 = a1;
    uint32_t bits[8];
    for (int j = 0; j < 4; ++j){
      uint32_t c, d2; tf2x32(s0, s1, (uint32_t)j, (uint32_t)(j+4), &c, &d2);
      bits[j] = c; bits[j+4] = d2;
    }
    for (int bq = 0; bq < NBATCH; ++bq) ra.r[i][bq] = tf_uniform_bits(bits[bq]);
#endif
  }

  hipLaunchKernelGGL(k_prep, dim3(NBLK), dim3(NTHR), 0, stream, X, centers, fsq);
  for (int i = 1; i < KC; ++i){
    hipLaunchKernelGGL(k_dist, dim3(NBLK), dim3(NTHR), 0, stream, X, centers, fsq, dmin);
    hipLaunchKernelGGL(k_select, dim3(NBATCH), dim3(NTHR), 0, stream, X, centers, dmin, ra, i);
  }
  for (int it = 0; it < MAXIT; ++it){
    hipLaunchKernelGGL(k_iter, dim3(NBLK), dim3(NTHR), 0, stream, X, centers, fsq, part, pnum);
    hipLaunchKernelGGL(k_reduce, dim3(64), dim3(NTHR), 0, stream, part, pnum, centers);
  }
}

// Round 7
// 5106.431 us; speedup vs baseline: 1.8928x; 1.8928x over previous
//
#include <hip/hip_runtime.h>
#include <stdint.h>
#include <string.h>

#define NBATCH 8
#define NSPK_  4
#define DIMS   512
#define TLEN   2000
#define KC     4
#define NPTS   8000            // points per batch
#define NBLK   1000            // Lloyd / dist / prep grid
#define NTHR   256
#define PPB    64              // points per block
#define BPB    125             // blocks per batch
#define MAXIT  100

#define THREEFRY_PARTITIONABLE 1

struct RArg { float r[3][NBATCH]; };

// ---- exact replica of numpy pairwise_sum (umath loops), stride in elements ----
__device__ float np_pw(const float* a, int n, int st){
  #pragma clang fp contract(off)
  if (n < 8){
    float r = 0.f;
    for (int i = 0; i < n; ++i) r += a[(long)i*st];
    return r;
  }
  if (n <= 128){
    float r0=a[0], r1=a[st], r2=a[2*st], r3=a[3*st],
          r4=a[4*st], r5=a[5*st], r6=a[6*st], r7=a[7*st];
    int i = 8;
    for (; i < n - (n & 7); i += 8){
      r0 += a[(long)(i+0)*st]; r1 += a[(long)(i+1)*st];
      r2 += a[(long)(i+2)*st]; r3 += a[(long)(i+3)*st];
      r4 += a[(long)(i+4)*st]; r5 += a[(long)(i+5)*st];
      r6 += a[(long)(i+6)*st]; r7 += a[(long)(i+7)*st];
    }
    float res = ((r0 + r1) + (r2 + r3)) + ((r4 + r5) + (r6 + r7));
    for (; i < n; ++i) res += a[(long)i*st];
    return res;
  }
  int n2 = n/2; n2 -= (n2 & 7);
  return np_pw(a, n2, st) + np_pw(a + (long)n2*st, n - n2, st);
}
__device__ float np_pw_sq(const float* a, int n, int st){
  #pragma clang fp contract(off)
  if (n < 8){
    float r = 0.f;
    for (int i = 0; i < n; ++i){ float x = a[(long)i*st]; float s = x*x; r += s; }
    return r;
  }
  if (n <= 128){
    float x0=a[0],x1=a[st],x2=a[2*st],x3=a[3*st],
          x4=a[4*st],x5=a[5*st],x6=a[6*st],x7=a[7*st];
    float r0=x0*x0, r1=x1*x1, r2=x2*x2, r3=x3*x3,
          r4=x4*x4, r5=x5*x5, r6=x6*x6, r7=x7*x7;
    int i = 8;
    for (; i < n - (n & 7); i += 8){
      float y0=a[(long)(i+0)*st], y1=a[(long)(i+1)*st], y2=a[(long)(i+2)*st], y3=a[(long)(i+3)*st];
      float y4=a[(long)(i+4)*st], y5=a[(long)(i+5)*st], y6=a[(long)(i+6)*st], y7=a[(long)(i+7)*st];
      r0 += y0*y0; r1 += y1*y1; r2 += y2*y2; r3 += y3*y3;
      r4 += y4*y4; r5 += y5*y5; r6 += y6*y6; r7 += y7*y7;
    }
    float res = ((r0 + r1) + (r2 + r3)) + ((r4 + r5) + (r6 + r7));
    for (; i < n; ++i){ float x = a[(long)i*st]; float s = x*x; res += s; }
    return res;
  }
  int n2 = n/2; n2 -= (n2 & 7);
  return np_pw_sq(a, n2, st) + np_pw_sq(a + (long)n2*st, n - n2, st);
}

// ======== phase 0: fsq via 4-leaf parallel np tree; center row 0; rows 1..3 = 0
__global__ __launch_bounds__(NTHR)
void k_prep(const float* __restrict__ X, float* __restrict__ C, float* __restrict__ fsq){
  const int blk = blockIdx.x, tid = threadIdx.x;
  const int q = tid >> 6, l = tid & 63;    // wave = quarter, lane = point
  __shared__ float red[4][64];

  const int P = blk*64 + l;                // 1000*64 = 64000 points
  const int bf = P / NPTS, gf = P - bf*NPTS;
  const int nf = gf / TLEN, tf = gf - nf*TLEN;
  red[q][l] = np_pw_sq(X + ((size_t)(bf*NSPK_ + nf)*DIMS + q*128)*TLEN + tf, 128, TLEN);
  __syncthreads();
  if (tid < 64)
    fsq[blk*64 + tid] = (red[0][tid] + red[1][tid]) + (red[2][tid] + red[3][tid]);

  if (blk < NBATCH){
    for (int d = tid; d < DIMS; d += NTHR)
      C[blk*KC*DIMS + d] = X[((size_t)(blk*NSPK_)*DIMS + d)*TLEN];
  } else if (blk < 2*NBATCH){
    int bb = blk - NBATCH;
    for (int e = tid; e < 3*DIMS; e += NTHR) C[bb*KC*DIMS + DIMS + e] = 0.f;
  }
}

// ======== init dist: dmin over all 4 rows (zero rows give fsq == reference :i+1 slice)
__global__ __launch_bounds__(NTHR)
void k_dist(const float* __restrict__ X, const float* __restrict__ C,
            const float* __restrict__ fsq, float* __restrict__ dmin){
  const int blk = blockIdx.x, tid = threadIdx.x;
  const int w = tid >> 6, l = tid & 63;
  const int b = blk / BPB;
  const int P = blk*PPB + l;
  const int g = P - b*NPTS;
  const int n = g / TLEN, t = g - n*TLEN;

  __shared__ __align__(16) float cent[DIMS*KC];
  __shared__ float red[4][KC][PPB];
  __shared__ float csq_s[KC];

  const float* Cb = C + b*KC*DIMS;
  #pragma unroll
  for (int j = 0; j < 8; ++j){
    int e = tid*8 + j;
    cent[e] = Cb[(e&3)*DIMS + (e>>2)];
  }
  { const float* ck = Cb + w*DIMS + l*8;
    float s = 0.f;
    #pragma unroll
    for (int j = 0; j < 8; ++j){ float c = ck[j]; s += c*c; }
    #pragma unroll
    for (int o = 32; o; o >>= 1) s += __shfl_xor(s, o, 64);
    if (l == 0) csq_s[w] = s;
  }
  __syncthreads();

  const float* xp = X + (((size_t)(b*NSPK_ + n)*DIMS) + w*128)*TLEN + t;
  const float4* c4p = (const float4*)cent + w*128;
  float a0=0,a1=0,a2=0,a3=0;
  #pragma unroll 8
  for (int dq = 0; dq < 128; ++dq){
    float x = xp[(size_t)dq*TLEN];
    float4 c = c4p[dq];
    a0 += x*c.x; a1 += x*c.y; a2 += x*c.z; a3 += x*c.w;
  }
  red[w][0][l]=a0; red[w][1][l]=a1; red[w][2][l]=a2; red[w][3][l]=a3;
  __syncthreads();
  if (tid < PPB){
    float A0 = red[0][0][l]+red[1][0][l]+red[2][0][l]+red[3][0][l];
    float A1 = red[0][1][l]+red[1][1][l]+red[2][1][l]+red[3][1][l];
    float A2 = red[0][2][l]+red[1][2][l]+red[2][2][l]+red[3][2][l];
    float A3 = red[0][3][l]+red[1][3][l]+red[2][3][l]+red[3][3][l];
    float fs = fsq[P];
    float dm = (fs + csq_s[0]) - 2.f*A0;
    dm = fminf(dm, (fs + csq_s[1]) - 2.f*A1);
    dm = fminf(dm, (fs + csq_s[2]) - 2.f*A2);
    dm = fminf(dm, (fs + csq_s[3]) - 2.f*A3);
    dmin[P] = dm;
  }
}

// ======== selection (np-exact): grid 8, one block per batch; writes center row i
__global__ __launch_bounds__(NTHR)
void k_select(const float* __restrict__ X, float* __restrict__ C,
              const float* __restrict__ dmin, RArg ra, int i){
  const int bs = blockIdx.x, tid = threadIdx.x;
  const int w = tid >> 6, l = tid & 63;
  __shared__ __align__(16) float sbuf[NPTS];   // 32 KB
  __shared__ __align__(16) float pbuf[NPTS];   // 32 KB
  __shared__ float fsh[1];
  __shared__ int   ired[4];
  float rT = ra.r[i-1][bs];

  for (int e = tid; e < NPTS; e += NTHR) sbuf[e] = dmin[bs*NPTS + e];
  __syncthreads();
  if (w == 0){
    const int chunk = l >> 3, idx = l & 7;
    const int offs[8] = {0,120,248,368,496,616,744,872};
    int off = chunk*1000 + offs[idx];
    int len = (idx==0 || idx==2 || idx==4) ? 120 : 128;
    float v = np_pw(sbuf + off, len, 1);
    #pragma unroll
    for (int o = 1; o < 64; o <<= 1) v = v + __shfl_xor(v, o, 64);
    if (l == 0) fsh[0] = v;
  }
  __syncthreads();
  float tot = fsh[0];
  for (int e = tid; e < NPTS; e += NTHR) sbuf[e] = sbuf[e] / tot;  // IEEE div like np
  __syncthreads();
  if (tid == 0){
    #pragma clang fp contract(off)
    float b0[32], b1[32];
    #pragma unroll
    for (int u = 0; u < 32; ++u) b0[u] = sbuf[u];
    float run = 0.f;
    for (int j = 0; j < NPTS; j += 64){
      #pragma unroll
      for (int u = 0; u < 32; ++u) b1[u] = sbuf[j + 32 + u];
      #pragma unroll
      for (int u = 0; u < 32; ++u){ run = run + b0[u]; pbuf[j + u] = run; }
      if (j + 64 < NPTS){
        #pragma unroll
        for (int u = 0; u < 32; ++u) b0[u] = sbuf[j + 64 + u];
      }
      #pragma unroll
      for (int u = 0; u < 32; ++u){ run = run + b1[u]; pbuf[j + 32 + u] = run; }
    }
  }
  __syncthreads();
  int cnt = 0;
  for (int e = tid; e < NPTS; e += NTHR) cnt += (pbuf[e] <= rT) ? 1 : 0;
  #pragma unroll
  for (int o = 32; o; o >>= 1) cnt += __shfl_xor(cnt, o, 64);
  if (l == 0) ired[w] = cnt;
  __syncthreads();
  int sel = (ired[0] + ired[1] + ired[2] + ired[3]) - 1;
  for (int d = tid; d < DIMS; d += NTHR){
    float v = 0.f;
    if (sel >= 0){
      int ns = sel / TLEN, ts = sel - ns*TLEN;
      v = X[((size_t)(bs*NSPK_ + ns)*DIMS + d)*TLEN + ts];
    }
    C[(bs*KC + i)*DIMS + d] = v;
  }
}

// reduce-scatter pair step (identical pairing to the verified v1 kernel)
#define RSTEP(lo_v, hi_v, off, bitset, dst) do {            \
    float snd_ = (bitset) ? (lo_v) : (hi_v);                \
    float kp_  = (bitset) ? (hi_v) : (lo_v);                \
    dst = kp_ + __shfl_xor(snd_, off, 64); } while (0)

// ======== Lloyd iteration v3: v1's coalesced (dgg,pq) loads + register prefetch
// (double-buffered x4) + register cluster-sums (no LDS tile) + redundant
// all-wave argmin (no serial section) + double-buffered red2 -> ONE barrier
// per round. Dot-reduction tree and combine order are IDENTICAL to the
// verified v1 kernel -> bit-identical assignments.
// part layout: [blk][d][k] floats (k innermost) -> coalesced stores & reads.
__global__ __launch_bounds__(NTHR, 3)
void k_iter(const float* __restrict__ X, const float* __restrict__ C,
            const float* __restrict__ fsq, float* __restrict__ part,
            int* __restrict__ pnum){
  const int blk = blockIdx.x, tid = threadIdx.x;
  const int w = tid >> 6, l = tid & 63;
  const int pq = tid & 3;
  const int dgg = tid >> 2;                 // 0..63 (d-row group)
  const int dl = l >> 2;                    // dgg within wave: 0..15
  const int b = blk / BPB;
  const int g0 = (blk - b*BPB)*PPB;

  __shared__ __align__(16) float red2[2][4][4][16]; // 2 KB double-buffered
  __shared__ float csq_s[KC];

  // csq (identical to v1: wave w computes cluster w)
  const float* Cb = C + b*KC*DIMS;
  { const float* ck = Cb + w*DIMS + l*8;
    float s = 0.f;
    #pragma unroll
    for (int j = 0; j < 8; ++j){ float c = ck[j]; s += c*c; }
    #pragma unroll
    for (int o = 32; o; o >>= 1) s += __shfl_xor(s, o, 64);
    if (l == 0) csq_s[w] = s * (1.f/512.f);
  }
  __syncthreads();                          // prologue barrier (csq ready)
  const float cs0 = csq_s[0], cs1 = csq_s[1], cs2 = csq_s[2], cs3 = csq_s[3];

  // fsq for the redundant-argmin lane (p = l & 15), one per round
  const int pl = l & 15;
  float fq[4];
  #pragma unroll
  for (int h = 0; h < 4; ++h)
    fq[h] = fsq[b*NPTS + g0 + h*16 + pl];

  // center registers: cr[dd] = {C[k=0..3][dd*64+dgg]} (C is L2-hot, 64 KB)
  float4 cr[8];
  #pragma unroll
  for (int dd = 0; dd < 8; ++dd){
    int d = dd*64 + dgg;
    cr[dd].x = Cb[0*DIMS + d];
    cr[dd].y = Cb[1*DIMS + d];
    cr[dd].z = Cb[2*DIMS + d];
    cr[dd].w = Cb[3*DIMS + d];
  }

  // prologue: load round 0's x-quad
  float4 x4[8];
  { const int gp = g0 + pq*4;
    const int n = gp / TLEN, t = gp - n*TLEN;
    const float* xr = X + ((size_t)(b*NSPK_ + n)*DIMS + dgg)*TLEN + t;
    #pragma unroll
    for (int dd = 0; dd < 8; ++dd)
      x4[dd] = *(const float4*)(xr + (size_t)dd*64*TLEN);
  }

  float4 acc[8];
  #pragma unroll
  for (int dd = 0; dd < 8; ++dd) acc[dd] = make_float4(0.f,0.f,0.f,0.f);
  int c0=0, c1=0, c2=0, c3=0;

  const bool hb0 = dl & 1, hb1 = dl & 2, hb2 = dl & 4, hb3 = dl & 8;

  #pragma unroll
  for (int h = 0; h < 4; ++h){
    // prefetch next round's quad FIRST -> latency hides under this round's work
    float4 x4n[8];
    if (h < 3){
      const int gp = g0 + (h+1)*16 + pq*4;  // 2000%4==0 -> quad never straddles n
      const int n = gp / TLEN, t = gp - n*TLEN;
      const float* xr = X + ((size_t)(b*NSPK_ + n)*DIMS + dgg)*TLEN + t;
      #pragma unroll
      for (int dd = 0; dd < 8; ++dd)
        x4n[dd] = *(const float4*)(xr + (size_t)dd*64*TLEN);
    }

    // dots (v1 order, bit-identical)
    float4 a0 = {0,0,0,0}, a1 = {0,0,0,0}, a2 = {0,0,0,0}, a3 = {0,0,0,0};
    #pragma unroll
    for (int dd = 0; dd < 8; ++dd){
      float4 c = cr[dd];
      a0.x += x4[dd].x*c.x; a0.y += x4[dd].x*c.y; a0.z += x4[dd].x*c.z; a0.w += x4[dd].x*c.w;
      a1.x += x4[dd].y*c.x; a1.y += x4[dd].y*c.y; a1.z += x4[dd].y*c.z; a1.w += x4[dd].y*c.w;
      a2.x += x4[dd].z*c.x; a2.y += x4[dd].z*c.y; a2.z += x4[dd].z*c.z; a2.w += x4[dd].z*c.w;
      a3.x += x4[dd].w*c.x; a3.y += x4[dd].w*c.y; a3.z += x4[dd].w*c.z; a3.w += x4[dd].w*c.w;
    }
    // reduce-scatter over the 16 dgg-lanes sharing pq (v1 verbatim: bit-identical)
    float t0,t1,t2,t3,t4,t5,t6,t7;
    RSTEP(a0.x, a0.y, 4, hb0, t0);
    RSTEP(a0.z, a0.w, 4, hb0, t1);
    RSTEP(a1.x, a1.y, 4, hb0, t2);
    RSTEP(a1.z, a1.w, 4, hb0, t3);
    RSTEP(a2.x, a2.y, 4, hb0, t4);
    RSTEP(a2.z, a2.w, 4, hb0, t5);
    RSTEP(a3.x, a3.y, 4, hb0, t6);
    RSTEP(a3.z, a3.w, 4, hb0, t7);
    float u0,u1,u2,u3;
    RSTEP(t0, t1, 8, hb1, u0);
    RSTEP(t2, t3, 8, hb1, u1);
    RSTEP(t4, t5, 8, hb1, u2);
    RSTEP(t6, t7, 8, hb1, u3);
    float v0,v1;
    RSTEP(u0, u1, 16, hb2, v0);
    RSTEP(u2, u3, 16, hb2, v1);
    float rr;
    RSTEP(v0, v1, 32, hb3, rr);
    red2[h&1][w][pq][dl] = rr;
    __syncthreads();                        // the ONLY barrier per round

    // redundant all-wave argmin (p = l&15; combine order identical to v1)
    {
      const int pqq = pl >> 2, jj = pl & 3;
      float4 A = {0,0,0,0};
      #pragma unroll
      for (int q = 0; q < 4; ++q){
        float4 v = ((const float4*)&red2[h&1][q][pqq][0])[jj];
        A.x += v.x; A.y += v.y; A.z += v.z; A.w += v.w;
      }
      float xs = fq[h] * (1.f/512.f);
      float e0 = (xs + cs0) - 2.f*(A.x*(1.f/512.f));
      float e1 = (xs + cs1) - 2.f*(A.y*(1.f/512.f));
      float e2 = (xs + cs2) - 2.f*(A.z*(1.f/512.f));
      float e3 = (xs + cs3) - 2.f*(A.w*(1.f/512.f));
      int bi = 0; float bv = e0;            // first-min == np.argmin
      if (e1 < bv){ bv = e1; bi = 1; }
      if (e2 < bv){ bv = e2; bi = 2; }
      if (e3 < bv){ bv = e3; bi = 3; }
      unsigned long long m0 = __ballot(bi==0), m1 = __ballot(bi==1);
      unsigned long long m2 = __ballot(bi==2), m3 = __ballot(bi==3);
      c0 += __popcll(m0 & 0xFFFFull); c1 += __popcll(m1 & 0xFFFFull);
      c2 += __popcll(m2 & 0xFFFFull); c3 += __popcll(m3 & 0xFFFFull);

      // cluster sums for MY 4 points (pq*4+j): masks from ballot bits,
      // register FMAs on the x4 already held -- no LDS tile.
      #pragma unroll
      for (int j = 0; j < 4; ++j){
        const int pj = pq*4 + j;
        float f0 = (float)((m0 >> pj) & 1ull);
        float f1 = (float)((m1 >> pj) & 1ull);
        float f2 = (float)((m2 >> pj) & 1ull);
        float f3 = (float)((m3 >> pj) & 1ull);
        #pragma unroll
        for (int dd = 0; dd < 8; ++dd){
          float xv = (j==0) ? x4[dd].x : (j==1) ? x4[dd].y : (j==2) ? x4[dd].z : x4[dd].w;
          acc[dd].x += xv*f0; acc[dd].y += xv*f1; acc[dd].z += xv*f2; acc[dd].w += xv*f3;
        }
      }
    }
    // rotate buffers (register rename under full unroll)
    if (h < 3){
      #pragma unroll
      for (int dd = 0; dd < 8; ++dd) x4[dd] = x4n[dd];
    }
  }

  // epilogue: reduce acc over the 4 pq lanes sharing each d (tree (0+1)+(2+3))
  #pragma unroll
  for (int dd = 0; dd < 8; ++dd){
    acc[dd].x += __shfl_xor(acc[dd].x, 1, 64);
    acc[dd].y += __shfl_xor(acc[dd].y, 1, 64);
    acc[dd].z += __shfl_xor(acc[dd].z, 1, 64);
    acc[dd].w += __shfl_xor(acc[dd].w, 1, 64);
    acc[dd].x += __shfl_xor(acc[dd].x, 2, 64);
    acc[dd].y += __shfl_xor(acc[dd].y, 2, 64);
    acc[dd].z += __shfl_xor(acc[dd].z, 2, 64);
    acc[dd].w += __shfl_xor(acc[dd].w, 2, 64);
  }
  // store part[blk][d][k]: lane (dgg,pq) writes component pq at d=dd*64+dgg
  // float offset = blk*2048 + dd*256 + tid  -> 1KB fully-coalesced per dd
  float* pb = part + (size_t)blk*DIMS*KC;
  #pragma unroll
  for (int dd = 0; dd < 8; ++dd){
    float v = (pq==0) ? acc[dd].x : (pq==1) ? acc[dd].y : (pq==2) ? acc[dd].z : acc[dd].w;
    pb[dd*256 + tid] = v;
  }
  if (tid == 0){
    int4 c4 = {c0, c1, c2, c3};
    *(int4*)&pnum[blk*4] = c4;              // counts identical in every lane
  }
}

// ======== reduce partials -> centers. grid 64: blk = bb*8 + seg(64 d's)
// part is [blk][d][k] float4 (k in components); sums j ascending per quarter.
__global__ __launch_bounds__(NTHR)
void k_reduce(const float* __restrict__ part, const int* __restrict__ pnum,
              float* __restrict__ C){
  const int blk = blockIdx.x, tid = threadIdx.x;
  const int seg = blk & 7, bb = blk >> 3;
  const int w = tid >> 6, l = tid & 63;
  __shared__ __align__(16) float4 red[4][64];
  __shared__ int4 nsw[4];

  int4 v = {0,0,0,0};
  if (tid < BPB) v = *(const int4*)&pnum[(bb*BPB + tid)*4];
  #pragma unroll
  for (int o = 32; o; o >>= 1){
    v.x += __shfl_xor(v.x, o, 64); v.y += __shfl_xor(v.y, o, 64);
    v.z += __shfl_xor(v.z, o, 64); v.w += __shfl_xor(v.w, o, 64);
  }
  if (l == 0) nsw[w] = v;

  int jb = (BPB*w) >> 2, je = (BPB*(w+1)) >> 2;   // fixed quarters of 125
  float4 s = {0,0,0,0};
  const float4* pp = (const float4*)part;
  for (int j = jb; j < je; ++j){
    float4 t = pp[(size_t)(bb*BPB + j)*DIMS + seg*64 + l];
    s.x += t.x; s.y += t.y; s.z += t.z; s.w += t.w;
  }
  red[w][l] = s;
  __syncthreads();
  if (tid < 64){
    float4 r0 = red[0][l], r1 = red[1][l], r2 = red[2][l], r3 = red[3][l];
    float tsx = r0.x + r1.x + r2.x + r3.x;
    float tsy = r0.y + r1.y + r2.y + r3.y;
    float tsz = r0.z + r1.z + r2.z + r3.z;
    float tsw = r0.w + r1.w + r2.w + r3.w;
    int4 n0 = nsw[0], n1 = nsw[1], n2 = nsw[2], n3 = nsw[3];
    float dx = (float)(n0.x+n1.x+n2.x+n3.x) + 1e-8f;
    float dy = (float)(n0.y+n1.y+n2.y+n3.y) + 1e-8f;
    float dz = (float)(n0.z+n1.z+n2.z+n3.z) + 1e-8f;
    float dw = (float)(n0.w+n1.w+n2.w+n3.w) + 1e-8f;
    float* Cp = C + bb*KC*DIMS + seg*64 + l;
    Cp[0]        = tsx / dx;
    Cp[DIMS]     = tsy / dy;
    Cp[2*DIMS]   = tsz / dz;
    Cp[3*DIMS]   = tsw / dw;
  }
}

// ======================= host: threefry2x32 (JAX-compatible) =======================
static inline uint32_t rotl_(uint32_t x, int r){ return (x << r) | (x >> (32 - r)); }
static void tf2x32(uint32_t k0, uint32_t k1, uint32_t x0, uint32_t x1,
                   uint32_t* o0, uint32_t* o1){
  static const int R0[4] = {13,15,26,6}, R1[4] = {17,29,16,24};
  uint32_t ks[3] = { k0, k1, k0 ^ k1 ^ 0x1BD11BDAu };
  x0 += ks[0]; x1 += ks[1];
  for (int g = 0; g < 5; ++g){
    const int* rot = (g & 1) ? R1 : R0;
    for (int r = 0; r < 4; ++r){ x0 += x1; x1 = rotl_(x1, rot[r]); x1 ^= x0; }
    x0 += ks[(g+1)%3];
    x1 += ks[(g+2)%3] + (uint32_t)(g+1);
  }
  *o0 = x0; *o1 = x1;
}
static float tf_uniform_bits(uint32_t bits){
  uint32_t u = (bits >> 9) | 0x3f800000u;
  float f; memcpy(&f, &u, 4);
  return f - 1.0f;
}

extern "C" void kernel_launch(void* const* d_in, const int* in_sizes, int n_in,
                              void* d_out, int out_size, void* d_ws, size_t ws_size,
                              hipStream_t stream) {
  (void)in_sizes; (void)n_in; (void)out_size; (void)ws_size;
  const float* X = (const float*)d_in[0];
  float* centers = (float*)d_out;                 // (8,4,512)

  char* w = (char*)d_ws;
  float* fsq  = (float*)w;  w += (size_t)NBATCH*NPTS*4;            // 256 KB
  float* dmin = (float*)w;  w += (size_t)NBATCH*NPTS*4;            // 256 KB
  float* part = (float*)w;  w += (size_t)NBLK*DIMS*KC*4;           // 8.2 MB [blk][d][k]
  int*   pnum = (int*)w;    w += (size_t)NBLK*KC*4;                // 16 KB

  RArg ra;
  uint32_t k0 = 0u, k1 = 1u;
  for (int i = 0; i < 3; ++i){
#if THREEFRY_PARTITIONABLE
    uint32_t nk0, nk1, s0, s1;
    tf2x32(k0, k1, 0u, 0u, &nk0, &nk1);
    tf2x32(k0, k1, 0u, 1u, &s0, &s1);
    k0 = nk0; k1 = nk1;
    for (int bq = 0; bq < NBATCH; ++bq){
      uint32_t b1v, b2v; tf2x32(s0, s1, 0u, (uint32_t)bq, &b1v, &b2v);
      ra.r[i][bq] = tf_uniform_bits(b1v ^ b2v);
    }
#else
    uint32_t a0, b0, a1, b1;
    tf2x32(k0, k1, 0u, 2u, &a0, &b0);
    tf2x32(k0, k1, 1u, 3u, &a1, &b1);
    uint32_t s0 = b0, s1 = b1;
    k0 = a0; k1 = a1;
    uint32_t bits[8];
    for (int j = 0; j < 4; ++j){
      uint32_t c, d2; tf2x32(s0, s1, (uint32_t)j, (uint32_t)(j+4), &c, &d2);
      bits[j] = c; bits[j+4] = d2;
    }
    for (int bq = 0; bq < NBATCH; ++bq) ra.r[i][bq] = tf_uniform_bits(bits[bq]);
#endif
  }

  hipLaunchKernelGGL(k_prep, dim3(NBLK), dim3(NTHR), 0, stream, X, centers, fsq);
  for (int i = 1; i < KC; ++i){
    hipLaunchKernelGGL(k_dist, dim3(NBLK), dim3(NTHR), 0, stream, X, centers, fsq, dmin);
    hipLaunchKernelGGL(k_select, dim3(NBATCH), dim3(NTHR), 0, stream, X, centers, dmin, ra, i);
  }
  for (int it = 0; it < MAXIT; ++it){
    hipLaunchKernelGGL(k_iter, dim3(NBLK), dim3(NTHR), 0, stream, X, centers, fsq, part, pnum);
    hipLaunchKernelGGL(k_reduce, dim3(64), dim3(NTHR), 0, stream, part, pnum, centers);
  }
}

// Round 8
// 4177.246 us; speedup vs baseline: 2.3139x; 1.2224x over previous
//
#include <hip/hip_runtime.h>
#include <stdint.h>
#include <string.h>

#define NBATCH 8
#define NSPK_  4
#define DIMS   512
#define TLEN   2000
#define KC     4
#define NPTS   8000            // points per batch
#define NBLK   1000            // Lloyd / dist / prep grid
#define NTHR   256
#define PPB    64              // points per block
#define BPB    125             // blocks per batch
#define MAXIT  100
#define RBLK   64              // k_reduce grid size (convergence quorum)

#define THREEFRY_PARTITIONABLE 1

struct RArg { float r[3][NBATCH]; };

// ---- exact replica of numpy pairwise_sum (umath loops), stride in elements ----
__device__ float np_pw(const float* a, int n, int st){
  #pragma clang fp contract(off)
  if (n < 8){
    float r = 0.f;
    for (int i = 0; i < n; ++i) r += a[(long)i*st];
    return r;
  }
  if (n <= 128){
    float r0=a[0], r1=a[st], r2=a[2*st], r3=a[3*st],
          r4=a[4*st], r5=a[5*st], r6=a[6*st], r7=a[7*st];
    int i = 8;
    for (; i < n - (n & 7); i += 8){
      r0 += a[(long)(i+0)*st]; r1 += a[(long)(i+1)*st];
      r2 += a[(long)(i+2)*st]; r3 += a[(long)(i+3)*st];
      r4 += a[(long)(i+4)*st]; r5 += a[(long)(i+5)*st];
      r6 += a[(long)(i+6)*st]; r7 += a[(long)(i+7)*st];
    }
    float res = ((r0 + r1) + (r2 + r3)) + ((r4 + r5) + (r6 + r7));
    for (; i < n; ++i) res += a[(long)i*st];
    return res;
  }
  int n2 = n/2; n2 -= (n2 & 7);
  return np_pw(a, n2, st) + np_pw(a + (long)n2*st, n - n2, st);
}
__device__ float np_pw_sq(const float* a, int n, int st){
  #pragma clang fp contract(off)
  if (n < 8){
    float r = 0.f;
    for (int i = 0; i < n; ++i){ float x = a[(long)i*st]; float s = x*x; r += s; }
    return r;
  }
  if (n <= 128){
    float x0=a[0],x1=a[st],x2=a[2*st],x3=a[3*st],
          x4=a[4*st],x5=a[5*st],x6=a[6*st],x7=a[7*st];
    float r0=x0*x0, r1=x1*x1, r2=x2*x2, r3=x3*x3,
          r4=x4*x4, r5=x5*x5, r6=x6*x6, r7=x7*x7;
    int i = 8;
    for (; i < n - (n & 7); i += 8){
      float y0=a[(long)(i+0)*st], y1=a[(long)(i+1)*st], y2=a[(long)(i+2)*st], y3=a[(long)(i+3)*st];
      float y4=a[(long)(i+4)*st], y5=a[(long)(i+5)*st], y6=a[(long)(i+6)*st], y7=a[(long)(i+7)*st];
      r0 += y0*y0; r1 += y1*y1; r2 += y2*y2; r3 += y3*y3;
      r4 += y4*y4; r5 += y5*y5; r6 += y6*y6; r7 += y7*y7;
    }
    float res = ((r0 + r1) + (r2 + r3)) + ((r4 + r5) + (r6 + r7));
    for (; i < n; ++i){ float x = a[(long)i*st]; float s = x*x; res += s; }
    return res;
  }
  int n2 = n/2; n2 -= (n2 & 7);
  return np_pw_sq(a, n2, st) + np_pw_sq(a + (long)n2*st, n - n2, st);
}

// ======== phase 0: fsq via 4-leaf parallel np tree; center row 0; rows 1..3 = 0
// also zeroes the convergence counters (workspace is poisoned by the harness).
__global__ __launch_bounds__(NTHR)
void k_prep(const float* __restrict__ X, float* __restrict__ C, float* __restrict__ fsq,
            int* __restrict__ cnt){
  const int blk = blockIdx.x, tid = threadIdx.x;
  const int q = tid >> 6, l = tid & 63;    // wave = quarter, lane = point
  __shared__ float red[4][64];

  const int P = blk*64 + l;                // 1000*64 = 64000 points
  const int bf = P / NPTS, gf = P - bf*NPTS;
  const int nf = gf / TLEN, tf = gf - nf*TLEN;
  red[q][l] = np_pw_sq(X + ((size_t)(bf*NSPK_ + nf)*DIMS + q*128)*TLEN + tf, 128, TLEN);
  __syncthreads();
  if (tid < 64)
    fsq[blk*64 + tid] = (red[0][tid] + red[1][tid]) + (red[2][tid] + red[3][tid]);

  if (blk < NBATCH){
    for (int d = tid; d < DIMS; d += NTHR)
      C[blk*KC*DIMS + d] = X[((size_t)(blk*NSPK_)*DIMS + d)*TLEN];
  } else if (blk < 2*NBATCH){
    int bb = blk - NBATCH;
    for (int e = tid; e < 3*DIMS; e += NTHR) C[bb*KC*DIMS + DIMS + e] = 0.f;
  } else if (blk == 2*NBATCH){
    for (int e = tid; e < MAXIT; e += NTHR) cnt[e] = 0;
  }
}

// ======== init dist: dmin over all 4 rows (zero rows give fsq == reference :i+1 slice)
__global__ __launch_bounds__(NTHR)
void k_dist(const float* __restrict__ X, const float* __restrict__ C,
            const float* __restrict__ fsq, float* __restrict__ dmin){
  const int blk = blockIdx.x, tid = threadIdx.x;
  const int w = tid >> 6, l = tid & 63;
  const int b = blk / BPB;
  const int P = blk*PPB + l;
  const int g = P - b*NPTS;
  const int n = g / TLEN, t = g - n*TLEN;

  __shared__ __align__(16) float cent[DIMS*KC];
  __shared__ float red[4][KC][PPB];
  __shared__ float csq_s[KC];

  const float* Cb = C + b*KC*DIMS;
  #pragma unroll
  for (int j = 0; j < 8; ++j){
    int e = tid*8 + j;
    cent[e] = Cb[(e&3)*DIMS + (e>>2)];
  }
  { const float* ck = Cb + w*DIMS + l*8;
    float s = 0.f;
    #pragma unroll
    for (int j = 0; j < 8; ++j){ float c = ck[j]; s += c*c; }
    #pragma unroll
    for (int o = 32; o; o >>= 1) s += __shfl_xor(s, o, 64);
    if (l == 0) csq_s[w] = s;
  }
  __syncthreads();

  const float* xp = X + (((size_t)(b*NSPK_ + n)*DIMS) + w*128)*TLEN + t;
  const float4* c4p = (const float4*)cent + w*128;
  float a0=0,a1=0,a2=0,a3=0;
  #pragma unroll 8
  for (int dq = 0; dq < 128; ++dq){
    float x = xp[(size_t)dq*TLEN];
    float4 c = c4p[dq];
    a0 += x*c.x; a1 += x*c.y; a2 += x*c.z; a3 += x*c.w;
  }
  red[w][0][l]=a0; red[w][1][l]=a1; red[w][2][l]=a2; red[w][3][l]=a3;
  __syncthreads();
  if (tid < PPB){
    float A0 = red[0][0][l]+red[1][0][l]+red[2][0][l]+red[3][0][l];
    float A1 = red[0][1][l]+red[1][1][l]+red[2][1][l]+red[3][1][l];
    float A2 = red[0][2][l]+red[1][2][l]+red[2][2][l]+red[3][2][l];
    float A3 = red[0][3][l]+red[1][3][l]+red[2][3][l]+red[3][3][l];
    float fs = fsq[P];
    float dm = (fs + csq_s[0]) - 2.f*A0;
    dm = fminf(dm, (fs + csq_s[1]) - 2.f*A1);
    dm = fminf(dm, (fs + csq_s[2]) - 2.f*A2);
    dm = fminf(dm, (fs + csq_s[3]) - 2.f*A3);
    dmin[P] = dm;
  }
}

// ======== selection (np-exact): grid 8, one block per batch; writes center row i
__global__ __launch_bounds__(NTHR)
void k_select(const float* __restrict__ X, float* __restrict__ C,
              const float* __restrict__ dmin, RArg ra, int i){
  const int bs = blockIdx.x, tid = threadIdx.x;
  const int w = tid >> 6, l = tid & 63;
  __shared__ __align__(16) float sbuf[NPTS];   // 32 KB
  __shared__ __align__(16) float pbuf[NPTS];   // 32 KB
  __shared__ float fsh[1];
  __shared__ int   ired[4];
  float rT = ra.r[i-1][bs];

  for (int e = tid; e < NPTS; e += NTHR) sbuf[e] = dmin[bs*NPTS + e];
  __syncthreads();
  if (w == 0){
    const int chunk = l >> 3, idx = l & 7;
    const int offs[8] = {0,120,248,368,496,616,744,872};
    int off = chunk*1000 + offs[idx];
    int len = (idx==0 || idx==2 || idx==4) ? 120 : 128;
    float v = np_pw(sbuf + off, len, 1);
    #pragma unroll
    for (int o = 1; o < 64; o <<= 1) v = v + __shfl_xor(v, o, 64);
    if (l == 0) fsh[0] = v;
  }
  __syncthreads();
  float tot = fsh[0];
  for (int e = tid; e < NPTS; e += NTHR) sbuf[e] = sbuf[e] / tot;  // IEEE div like np
  __syncthreads();
  if (tid == 0){
    #pragma clang fp contract(off)
    float b0[32], b1[32];
    #pragma unroll
    for (int u = 0; u < 32; ++u) b0[u] = sbuf[u];
    float run = 0.f;
    for (int j = 0; j < NPTS; j += 64){
      #pragma unroll
      for (int u = 0; u < 32; ++u) b1[u] = sbuf[j + 32 + u];
      #pragma unroll
      for (int u = 0; u < 32; ++u){ run = run + b0[u]; pbuf[j + u] = run; }
      if (j + 64 < NPTS){
        #pragma unroll
        for (int u = 0; u < 32; ++u) b0[u] = sbuf[j + 64 + u];
      }
      #pragma unroll
      for (int u = 0; u < 32; ++u){ run = run + b1[u]; pbuf[j + 32 + u] = run; }
    }
  }
  __syncthreads();
  int cnt = 0;
  for (int e = tid; e < NPTS; e += NTHR) cnt += (pbuf[e] <= rT) ? 1 : 0;
  #pragma unroll
  for (int o = 32; o; o >>= 1) cnt += __shfl_xor(cnt, o, 64);
  if (l == 0) ired[w] = cnt;
  __syncthreads();
  int sel = (ired[0] + ired[1] + ired[2] + ired[3]) - 1;
  for (int d = tid; d < DIMS; d += NTHR){
    float v = 0.f;
    if (sel >= 0){
      int ns = sel / TLEN, ts = sel - ns*TLEN;
      v = X[((size_t)(bs*NSPK_ + ns)*DIMS + d)*TLEN + ts];
    }
    C[(bs*KC + i)*DIMS + d] = v;
  }
}

// reduce-scatter pair step (identical pairing to the verified v1 kernel)
#define RSTEP(lo_v, hi_v, off, bitset, dst) do {            \
    float snd_ = (bitset) ? (lo_v) : (hi_v);                \
    float kp_  = (bitset) ? (hi_v) : (lo_v);                \
    dst = kp_ + __shfl_xor(snd_, off, 64); } while (0)

// ======== Lloyd iteration v3 (verified bit-exact) + fixed-point early-exit.
// If cnt[it-1]==RBLK, centers reached a bitwise fixed point at a previous
// iteration: the deterministic map g(C) makes all later iterations no-ops.
__global__ __launch_bounds__(NTHR, 3)
void k_iter(const float* __restrict__ X, const float* __restrict__ C,
            const float* __restrict__ fsq, float* __restrict__ part,
            int* __restrict__ pnum, const int* __restrict__ cnt, int it){
  if (it > 0 && cnt[it-1] == RBLK) return;   // converged: C already final

  const int blk = blockIdx.x, tid = threadIdx.x;
  const int w = tid >> 6, l = tid & 63;
  const int pq = tid & 3;
  const int dgg = tid >> 2;                 // 0..63 (d-row group)
  const int dl = l >> 2;                    // dgg within wave: 0..15
  const int b = blk / BPB;
  const int g0 = (blk - b*BPB)*PPB;

  __shared__ __align__(16) float red2[2][4][4][16]; // 2 KB double-buffered
  __shared__ float csq_s[KC];

  // csq (identical to v1: wave w computes cluster w)
  const float* Cb = C + b*KC*DIMS;
  { const float* ck = Cb + w*DIMS + l*8;
    float s = 0.f;
    #pragma unroll
    for (int j = 0; j < 8; ++j){ float c = ck[j]; s += c*c; }
    #pragma unroll
    for (int o = 32; o; o >>= 1) s += __shfl_xor(s, o, 64);
    if (l == 0) csq_s[w] = s * (1.f/512.f);
  }
  __syncthreads();                          // prologue barrier (csq ready)
  const float cs0 = csq_s[0], cs1 = csq_s[1], cs2 = csq_s[2], cs3 = csq_s[3];

  // fsq for the redundant-argmin lane (p = l & 15), one per round
  const int pl = l & 15;
  float fq[4];
  #pragma unroll
  for (int h = 0; h < 4; ++h)
    fq[h] = fsq[b*NPTS + g0 + h*16 + pl];

  // center registers: cr[dd] = {C[k=0..3][dd*64+dgg]} (C is L2-hot, 64 KB)
  float4 cr[8];
  #pragma unroll
  for (int dd = 0; dd < 8; ++dd){
    int d = dd*64 + dgg;
    cr[dd].x = Cb[0*DIMS + d];
    cr[dd].y = Cb[1*DIMS + d];
    cr[dd].z = Cb[2*DIMS + d];
    cr[dd].w = Cb[3*DIMS + d];
  }

  // prologue: load round 0's x-quad
  float4 x4[8];
  { const int gp = g0 + pq*4;
    const int n = gp / TLEN, t = gp - n*TLEN;
    const float* xr = X + ((size_t)(b*NSPK_ + n)*DIMS + dgg)*TLEN + t;
    #pragma unroll
    for (int dd = 0; dd < 8; ++dd)
      x4[dd] = *(const float4*)(xr + (size_t)dd*64*TLEN);
  }

  float4 acc[8];
  #pragma unroll
  for (int dd = 0; dd < 8; ++dd) acc[dd] = make_float4(0.f,0.f,0.f,0.f);
  int c0=0, c1=0, c2=0, c3=0;

  const bool hb0 = dl & 1, hb1 = dl & 2, hb2 = dl & 4, hb3 = dl & 8;

  #pragma unroll
  for (int h = 0; h < 4; ++h){
    // prefetch next round's quad FIRST -> latency hides under this round's work
    float4 x4n[8];
    if (h < 3){
      const int gp = g0 + (h+1)*16 + pq*4;  // 2000%4==0 -> quad never straddles n
      const int n = gp / TLEN, t = gp - n*TLEN;
      const float* xr = X + ((size_t)(b*NSPK_ + n)*DIMS + dgg)*TLEN + t;
      #pragma unroll
      for (int dd = 0; dd < 8; ++dd)
        x4n[dd] = *(const float4*)(xr + (size_t)dd*64*TLEN);
    }

    // dots (v1 order, bit-identical)
    float4 a0 = {0,0,0,0}, a1 = {0,0,0,0}, a2 = {0,0,0,0}, a3 = {0,0,0,0};
    #pragma unroll
    for (int dd = 0; dd < 8; ++dd){
      float4 c = cr[dd];
      a0.x += x4[dd].x*c.x; a0.y += x4[dd].x*c.y; a0.z += x4[dd].x*c.z; a0.w += x4[dd].x*c.w;
      a1.x += x4[dd].y*c.x; a1.y += x4[dd].y*c.y; a1.z += x4[dd].y*c.z; a1.w += x4[dd].y*c.w;
      a2.x += x4[dd].z*c.x; a2.y += x4[dd].z*c.y; a2.z += x4[dd].z*c.z; a2.w += x4[dd].z*c.w;
      a3.x += x4[dd].w*c.x; a3.y += x4[dd].w*c.y; a3.z += x4[dd].w*c.z; a3.w += x4[dd].w*c.w;
    }
    // reduce-scatter over the 16 dgg-lanes sharing pq (v1 verbatim: bit-identical)
    float t0,t1,t2,t3,t4,t5,t6,t7;
    RSTEP(a0.x, a0.y, 4, hb0, t0);
    RSTEP(a0.z, a0.w, 4, hb0, t1);
    RSTEP(a1.x, a1.y, 4, hb0, t2);
    RSTEP(a1.z, a1.w, 4, hb0, t3);
    RSTEP(a2.x, a2.y, 4, hb0, t4);
    RSTEP(a2.z, a2.w, 4, hb0, t5);
    RSTEP(a3.x, a3.y, 4, hb0, t6);
    RSTEP(a3.z, a3.w, 4, hb0, t7);
    float u0,u1,u2,u3;
    RSTEP(t0, t1, 8, hb1, u0);
    RSTEP(t2, t3, 8, hb1, u1);
    RSTEP(t4, t5, 8, hb1, u2);
    RSTEP(t6, t7, 8, hb1, u3);
    float v0,v1;
    RSTEP(u0, u1, 16, hb2, v0);
    RSTEP(u2, u3, 16, hb2, v1);
    float rr;
    RSTEP(v0, v1, 32, hb3, rr);
    red2[h&1][w][pq][dl] = rr;
    __syncthreads();                        // the ONLY barrier per round

    // redundant all-wave argmin (p = l&15; combine order identical to v1)
    {
      const int pqq = pl >> 2, jj = pl & 3;
      float4 A = {0,0,0,0};
      #pragma unroll
      for (int q = 0; q < 4; ++q){
        float4 v = ((const float4*)&red2[h&1][q][pqq][0])[jj];
        A.x += v.x; A.y += v.y; A.z += v.z; A.w += v.w;
      }
      float xs = fq[h] * (1.f/512.f);
      float e0 = (xs + cs0) - 2.f*(A.x*(1.f/512.f));
      float e1 = (xs + cs1) - 2.f*(A.y*(1.f/512.f));
      float e2 = (xs + cs2) - 2.f*(A.z*(1.f/512.f));
      float e3 = (xs + cs3) - 2.f*(A.w*(1.f/512.f));
      int bi = 0; float bv = e0;            // first-min == np.argmin
      if (e1 < bv){ bv = e1; bi = 1; }
      if (e2 < bv){ bv = e2; bi = 2; }
      if (e3 < bv){ bv = e3; bi = 3; }
      unsigned long long m0 = __ballot(bi==0), m1 = __ballot(bi==1);
      unsigned long long m2 = __ballot(bi==2), m3 = __ballot(bi==3);
      c0 += __popcll(m0 & 0xFFFFull); c1 += __popcll(m1 & 0xFFFFull);
      c2 += __popcll(m2 & 0xFFFFull); c3 += __popcll(m3 & 0xFFFFull);

      // cluster sums for MY 4 points (pq*4+j): masks from ballot bits,
      // register FMAs on the x4 already held -- no LDS tile.
      #pragma unroll
      for (int j = 0; j < 4; ++j){
        const int pj = pq*4 + j;
        float f0 = (float)((m0 >> pj) & 1ull);
        float f1 = (float)((m1 >> pj) & 1ull);
        float f2 = (float)((m2 >> pj) & 1ull);
        float f3 = (float)((m3 >> pj) & 1ull);
        #pragma unroll
        for (int dd = 0; dd < 8; ++dd){
          float xv = (j==0) ? x4[dd].x : (j==1) ? x4[dd].y : (j==2) ? x4[dd].z : x4[dd].w;
          acc[dd].x += xv*f0; acc[dd].y += xv*f1; acc[dd].z += xv*f2; acc[dd].w += xv*f3;
        }
      }
    }
    // rotate buffers (register rename under full unroll)
    if (h < 3){
      #pragma unroll
      for (int dd = 0; dd < 8; ++dd) x4[dd] = x4n[dd];
    }
  }

  // epilogue: reduce acc over the 4 pq lanes sharing each d (tree (0+1)+(2+3))
  #pragma unroll
  for (int dd = 0; dd < 8; ++dd){
    acc[dd].x += __shfl_xor(acc[dd].x, 1, 64);
    acc[dd].y += __shfl_xor(acc[dd].y, 1, 64);
    acc[dd].z += __shfl_xor(acc[dd].z, 1, 64);
    acc[dd].w += __shfl_xor(acc[dd].w, 1, 64);
    acc[dd].x += __shfl_xor(acc[dd].x, 2, 64);
    acc[dd].y += __shfl_xor(acc[dd].y, 2, 64);
    acc[dd].z += __shfl_xor(acc[dd].z, 2, 64);
    acc[dd].w += __shfl_xor(acc[dd].w, 2, 64);
  }
  // store part[blk][d][k]: lane (dgg,pq) writes component pq at d=dd*64+dgg
  float* pb = part + (size_t)blk*DIMS*KC;
  #pragma unroll
  for (int dd = 0; dd < 8; ++dd){
    float v = (pq==0) ? acc[dd].x : (pq==1) ? acc[dd].y : (pq==2) ? acc[dd].z : acc[dd].w;
    pb[dd*256 + tid] = v;
  }
  if (tid == 0){
    int4 c4 = {c0, c1, c2, c3};
    *(int4*)&pnum[blk*4] = c4;              // counts identical in every lane
  }
}

// ======== reduce partials -> centers. grid RBLK=64: blk = bb*8 + seg(64 d's)
// part is [blk][d][k] float4 (k in components); sums j ascending per quarter.
// Bitwise-compares new centers with live C; a fully-unchanged block votes in
// cnt[it]. cnt[it]==RBLK => fixed point (sticky via the early-exit path).
__global__ __launch_bounds__(NTHR)
void k_reduce(const float* __restrict__ part, const int* __restrict__ pnum,
              float* __restrict__ C, int* __restrict__ cnt, int it){
  if (it > 0 && cnt[it-1] == RBLK){
    if (threadIdx.x == 0) atomicAdd(&cnt[it], 1);   // propagate convergence
    return;
  }
  const int blk = blockIdx.x, tid = threadIdx.x;
  const int seg = blk & 7, bb = blk >> 3;
  const int w = tid >> 6, l = tid & 63;
  __shared__ __align__(16) float4 red[4][64];
  __shared__ int4 nsw[4];

  int4 v = {0,0,0,0};
  if (tid < BPB) v = *(const int4*)&pnum[(bb*BPB + tid)*4];
  #pragma unroll
  for (int o = 32; o; o >>= 1){
    v.x += __shfl_xor(v.x, o, 64); v.y += __shfl_xor(v.y, o, 64);
    v.z += __shfl_xor(v.z, o, 64); v.w += __shfl_xor(v.w, o, 64);
  }
  if (l == 0) nsw[w] = v;

  int jb = (BPB*w) >> 2, je = (BPB*(w+1)) >> 2;   // fixed quarters of 125
  float4 s = {0,0,0,0};
  const float4* pp = (const float4*)part;
  for (int j = jb; j < je; ++j){
    float4 t = pp[(size_t)(bb*BPB + j)*DIMS + seg*64 + l];
    s.x += t.x; s.y += t.y; s.z += t.z; s.w += t.w;
  }
  red[w][l] = s;
  __syncthreads();
  if (tid < 64){
    float4 r0 = red[0][l], r1 = red[1][l], r2 = red[2][l], r3 = red[3][l];
    float tsx = r0.x + r1.x + r2.x + r3.x;
    float tsy = r0.y + r1.y + r2.y + r3.y;
    float tsz = r0.z + r1.z + r2.z + r3.z;
    float tsw = r0.w + r1.w + r2.w + r3.w;
    int4 n0 = nsw[0], n1 = nsw[1], n2 = nsw[2], n3 = nsw[3];
    float dx = (float)(n0.x+n1.x+n2.x+n3.x) + 1e-8f;
    float dy = (float)(n0.y+n1.y+n2.y+n3.y) + 1e-8f;
    float dz = (float)(n0.z+n1.z+n2.z+n3.z) + 1e-8f;
    float dw = (float)(n0.w+n1.w+n2.w+n3.w) + 1e-8f;
    float nx = tsx / dx, ny = tsy / dy, nz = tsz / dz, nw2 = tsw / dw;
    float* Cp = C + bb*KC*DIMS + seg*64 + l;
    bool diff = (__float_as_uint(nx)  != __float_as_uint(Cp[0]))
             || (__float_as_uint(ny)  != __float_as_uint(Cp[DIMS]))
             || (__float_as_uint(nz)  != __float_as_uint(Cp[2*DIMS]))
             || (__float_as_uint(nw2) != __float_as_uint(Cp[3*DIMS]));
    Cp[0]        = nx;
    Cp[DIMS]     = ny;
    Cp[2*DIMS]   = nz;
    Cp[3*DIMS]   = nw2;
    unsigned long long m = __ballot(diff);   // wave 0 fully active here
    if (l == 0 && m == 0ull) atomicAdd(&cnt[it], 1);
  }
}

// ======================= host: threefry2x32 (JAX-compatible) =======================
static inline uint32_t rotl_(uint32_t x, int r){ return (x << r) | (x >> (32 - r)); }
static void tf2x32(uint32_t k0, uint32_t k1, uint32_t x0, uint32_t x1,
                   uint32_t* o0, uint32_t* o1){
  static const int R0[4] = {13,15,26,6}, R1[4] = {17,29,16,24};
  uint32_t ks[3] = { k0, k1, k0 ^ k1 ^ 0x1BD11BDAu };
  x0 += ks[0]; x1 += ks[1];
  for (int g = 0; g < 5; ++g){
    const int* rot = (g & 1) ? R1 : R0;
    for (int r = 0; r < 4; ++r){ x0 += x1; x1 = rotl_(x1, rot[r]); x1 ^= x0; }
    x0 += ks[(g+1)%3];
    x1 += ks[(g+2)%3] + (uint32_t)(g+1);
  }
  *o0 = x0; *o1 = x1;
}
static float tf_uniform_bits(uint32_t bits){
  uint32_t u = (bits >> 9) | 0x3f800000u;
  float f; memcpy(&f, &u, 4);
  return f - 1.0f;
}

extern "C" void kernel_launch(void* const* d_in, const int* in_sizes, int n_in,
                              void* d_out, int out_size, void* d_ws, size_t ws_size,
                              hipStream_t stream) {
  (void)in_sizes; (void)n_in; (void)out_size; (void)ws_size;
  const float* X = (const float*)d_in[0];
  float* centers = (float*)d_out;                 // (8,4,512)

  char* w = (char*)d_ws;
  float* fsq  = (float*)w;  w += (size_t)NBATCH*NPTS*4;            // 256 KB
  float* dmin = (float*)w;  w += (size_t)NBATCH*NPTS*4;            // 256 KB
  float* part = (float*)w;  w += (size_t)NBLK*DIMS*KC*4;           // 8.2 MB [blk][d][k]
  int*   pnum = (int*)w;    w += (size_t)NBLK*KC*4;                // 16 KB
  int*   cnt  = (int*)w;    w += (size_t)MAXIT*4;                  // 400 B

  RArg ra;
  uint32_t k0 = 0u, k1 = 1u;
  for (int i = 0; i < 3; ++i){
#if THREEFRY_PARTITIONABLE
    uint32_t nk0, nk1, s0, s1;
    tf2x32(k0, k1, 0u, 0u, &nk0, &nk1);
    tf2x32(k0, k1, 0u, 1u, &s0, &s1);
    k0 = nk0; k1 = nk1;
    for (int bq = 0; bq < NBATCH; ++bq){
      uint32_t b1v, b2v; tf2x32(s0, s1, 0u, (uint32_t)bq, &b1v, &b2v);
      ra.r[i][bq] = tf_uniform_bits(b1v ^ b2v);
    }
#else
    uint32_t a0, b0, a1, b1;
    tf2x32(k0, k1, 0u, 2u, &a0, &b0);
    tf2x32(k0, k1, 1u, 3u, &a1, &b1);
    uint32_t s0 = b0, s1 = b1;
    k0 = a0; k1 = a1;
    uint32_t bits[8];
    for (int j = 0; j < 4; ++j){
      uint32_t c, d2; tf2x32(s0, s1, (uint32_t)j, (uint32_t)(j+4), &c, &d2);
      bits[j] = c; bits[j+4] = d2;
    }
    for (int bq = 0; bq < NBATCH; ++bq) ra.r[i][bq] = tf_uniform_bits(bits[bq]);
#endif
  }

  hipLaunchKernelGGL(k_prep, dim3(NBLK), dim3(NTHR), 0, stream, X, centers, fsq, cnt);
  for (int i = 1; i < KC; ++i){
    hipLaunchKernelGGL(k_dist, dim3(NBLK), dim3(NTHR), 0, stream, X, centers, fsq, dmin);
    hipLaunchKernelGGL(k_select, dim3(NBATCH), dim3(NTHR), 0, stream, X, centers, dmin, ra, i);
  }
  for (int it = 0; it < MAXIT; ++it){
    hipLaunchKernelGGL(k_iter, dim3(NBLK), dim3(NTHR), 0, stream, X, centers, fsq, part, pnum, cnt, it);
    hipLaunchKernelGGL(k_reduce, dim3(RBLK), dim3(NTHR), 0, stream, part, pnum, centers, cnt, it);
  }
}

// Round 14
// 3671.940 us; speedup vs baseline: 2.6323x; 1.1376x over previous
//
#include <hip/hip_runtime.h>
#include <stdint.h>
#include <string.h>

#define NBATCH 8
#define NSPK_  4
#define DIMS   512
#define TLEN   2000
#define KC     4
#define NPTS   8000            // points per batch
#define NBLK   1000            // Lloyd / dist / prep grid
#define NTHR   256
#define PPB    64              // points per block
#define BPB    125             // blocks per batch
#define MAXIT  100
#define RBLK   64              // k_reduce grid size (8 batches x 8 segs)

#define THREEFRY_PARTITIONABLE 1

struct RArg { float r[3][NBATCH]; };

// ---- exact replica of numpy pairwise_sum (umath loops), stride in elements ----
__device__ float np_pw(const float* a, int n, int st){
  #pragma clang fp contract(off)
  if (n < 8){
    float r = 0.f;
    for (int i = 0; i < n; ++i) r += a[(long)i*st];
    return r;
  }
  if (n <= 128){
    float r0=a[0], r1=a[st], r2=a[2*st], r3=a[3*st],
          r4=a[4*st], r5=a[5*st], r6=a[6*st], r7=a[7*st];
    int i = 8;
    for (; i < n - (n & 7); i += 8){
      r0 += a[(long)(i+0)*st]; r1 += a[(long)(i+1)*st];
      r2 += a[(long)(i+2)*st]; r3 += a[(long)(i+3)*st];
      r4 += a[(long)(i+4)*st]; r5 += a[(long)(i+5)*st];
      r6 += a[(long)(i+6)*st]; r7 += a[(long)(i+7)*st];
    }
    float res = ((r0 + r1) + (r2 + r3)) + ((r4 + r5) + (r6 + r7));
    for (; i < n; ++i) res += a[(long)i*st];
    return res;
  }
  int n2 = n/2; n2 -= (n2 & 7);
  return np_pw(a, n2, st) + np_pw(a + (long)n2*st, n - n2, st);
}
__device__ float np_pw_sq(const float* a, int n, int st){
  #pragma clang fp contract(off)
  if (n < 8){
    float r = 0.f;
    for (int i = 0; i < n; ++i){ float x = a[(long)i*st]; float s = x*x; r += s; }
    return r;
  }
  if (n <= 128){
    float x0=a[0],x1=a[st],x2=a[2*st],x3=a[3*st],
          x4=a[4*st],x5=a[5*st],x6=a[6*st],x7=a[7*st];
    float r0=x0*x0, r1=x1*x1, r2=x2*x2, r3=x3*x3,
          r4=x4*x4, r5=x5*x5, r6=x6*x6, r7=x7*x7;
    int i = 8;
    for (; i < n - (n & 7); i += 8){
      float y0=a[(long)(i+0)*st], y1=a[(long)(i+1)*st], y2=a[(long)(i+2)*st], y3=a[(long)(i+3)*st];
      float y4=a[(long)(i+4)*st], y5=a[(long)(i+5)*st], y6=a[(long)(i+6)*st], y7=a[(long)(i+7)*st];
      r0 += y0*y0; r1 += y1*y1; r2 += y2*y2; r3 += y3*y3;
      r4 += y4*y4; r5 += y5*y5; r6 += y6*y6; r7 += y7*y7;
    }
    float res = ((r0 + r1) + (r2 + r3)) + ((r4 + r5) + (r6 + r7));
    for (; i < n; ++i){ float x = a[(long)i*st]; float s = x*x; res += s; }
    return res;
  }
  int n2 = n/2; n2 -= (n2 & 7);
  return np_pw_sq(a, n2, st) + np_pw_sq(a + (long)n2*st, n - n2, st);
}

// ======== phase 0: fsq via 4-leaf parallel np tree; center row 0; rows 1..3 = 0
// also seeds Cprev with a NaN sentinel (0xFFFFFFFF) so iteration 0 never
// looks converged (finite data can never produce that bit pattern).
__global__ __launch_bounds__(NTHR)
void k_prep(const float* __restrict__ X, float* __restrict__ C,
            float* __restrict__ Cprev, float* __restrict__ fsq){
  const int blk = blockIdx.x, tid = threadIdx.x;
  const int q = tid >> 6, l = tid & 63;    // wave = quarter, lane = point
  __shared__ float red[4][64];

  const int P = blk*64 + l;                // 1000*64 = 64000 points
  const int bf = P / NPTS, gf = P - bf*NPTS;
  const int nf = gf / TLEN, tf = gf - nf*TLEN;
  red[q][l] = np_pw_sq(X + ((size_t)(bf*NSPK_ + nf)*DIMS + q*128)*TLEN + tf, 128, TLEN);
  __syncthreads();
  if (tid < 64)
    fsq[blk*64 + tid] = (red[0][tid] + red[1][tid]) + (red[2][tid] + red[3][tid]);

  if (blk < NBATCH){
    for (int d = tid; d < DIMS; d += NTHR)
      C[blk*KC*DIMS + d] = X[((size_t)(blk*NSPK_)*DIMS + d)*TLEN];
  } else if (blk < 2*NBATCH){
    int bb = blk - NBATCH;
    for (int e = tid; e < 3*DIMS; e += NTHR) C[bb*KC*DIMS + DIMS + e] = 0.f;
    for (int e = tid; e < KC*DIMS; e += NTHR)
      ((uint32_t*)Cprev)[bb*KC*DIMS + e] = 0xFFFFFFFFu;   // sentinel != any C
  }
}

// ======== init dist: dmin over all 4 rows (zero rows give fsq == reference :i+1 slice)
__global__ __launch_bounds__(NTHR)
void k_dist(const float* __restrict__ X, const float* __restrict__ C,
            const float* __restrict__ fsq, float* __restrict__ dmin){
  const int blk = blockIdx.x, tid = threadIdx.x;
  const int w = tid >> 6, l = tid & 63;
  const int b = blk / BPB;
  const int P = blk*PPB + l;
  const int g = P - b*NPTS;
  const int n = g / TLEN, t = g - n*TLEN;

  __shared__ __align__(16) float cent[DIMS*KC];
  __shared__ float red[4][KC][PPB];
  __shared__ float csq_s[KC];

  const float* Cb = C + b*KC*DIMS;
  #pragma unroll
  for (int j = 0; j < 8; ++j){
    int e = tid*8 + j;
    cent[e] = Cb[(e&3)*DIMS + (e>>2)];
  }
  { const float* ck = Cb + w*DIMS + l*8;
    float s = 0.f;
    #pragma unroll
    for (int j = 0; j < 8; ++j){ float c = ck[j]; s += c*c; }
    #pragma unroll
    for (int o = 32; o; o >>= 1) s += __shfl_xor(s, o, 64);
    if (l == 0) csq_s[w] = s;
  }
  __syncthreads();

  const float* xp = X + (((size_t)(b*NSPK_ + n)*DIMS) + w*128)*TLEN + t;
  const float4* c4p = (const float4*)cent + w*128;
  float a0=0,a1=0,a2=0,a3=0;
  #pragma unroll 8
  for (int dq = 0; dq < 128; ++dq){
    float x = xp[(size_t)dq*TLEN];
    float4 c = c4p[dq];
    a0 += x*c.x; a1 += x*c.y; a2 += x*c.z; a3 += x*c.w;
  }
  red[w][0][l]=a0; red[w][1][l]=a1; red[w][2][l]=a2; red[w][3][l]=a3;
  __syncthreads();
  if (tid < PPB){
    float A0 = red[0][0][l]+red[1][0][l]+red[2][0][l]+red[3][0][l];
    float A1 = red[0][1][l]+red[1][1][l]+red[2][1][l]+red[3][1][l];
    float A2 = red[0][2][l]+red[1][2][l]+red[2][2][l]+red[3][2][l];
    float A3 = red[0][3][l]+red[1][3][l]+red[2][3][l]+red[3][3][l];
    float fs = fsq[P];
    float dm = (fs + csq_s[0]) - 2.f*A0;
    dm = fminf(dm, (fs + csq_s[1]) - 2.f*A1);
    dm = fminf(dm, (fs + csq_s[2]) - 2.f*A2);
    dm = fminf(dm, (fs + csq_s[3]) - 2.f*A3);
    dmin[P] = dm;
  }
}

// ======== selection (np-exact): grid 8, one block per batch; writes center row i
__global__ __launch_bounds__(NTHR)
void k_select(const float* __restrict__ X, float* __restrict__ C,
              const float* __restrict__ dmin, RArg ra, int i){
  const int bs = blockIdx.x, tid = threadIdx.x;
  const int w = tid >> 6, l = tid & 63;
  __shared__ __align__(16) float sbuf[NPTS];   // 32 KB
  __shared__ __align__(16) float pbuf[NPTS];   // 32 KB
  __shared__ float fsh[1];
  __shared__ int   ired[4];
  float rT = ra.r[i-1][bs];

  for (int e = tid; e < NPTS; e += NTHR) sbuf[e] = dmin[bs*NPTS + e];
  __syncthreads();
  if (w == 0){
    const int chunk = l >> 3, idx = l & 7;
    const int offs[8] = {0,120,248,368,496,616,744,872};
    int off = chunk*1000 + offs[idx];
    int len = (idx==0 || idx==2 || idx==4) ? 120 : 128;
    float v = np_pw(sbuf + off, len, 1);
    #pragma unroll
    for (int o = 1; o < 64; o <<= 1) v = v + __shfl_xor(v, o, 64);
    if (l == 0) fsh[0] = v;
  }
  __syncthreads();
  float tot = fsh[0];
  for (int e = tid; e < NPTS; e += NTHR) sbuf[e] = sbuf[e] / tot;  // IEEE div like np
  __syncthreads();
  if (tid == 0){
    #pragma clang fp contract(off)
    float b0[32], b1[32];
    #pragma unroll
    for (int u = 0; u < 32; ++u) b0[u] = sbuf[u];
    float run = 0.f;
    for (int j = 0; j < NPTS; j += 64){
      #pragma unroll
      for (int u = 0; u < 32; ++u) b1[u] = sbuf[j + 32 + u];
      #pragma unroll
      for (int u = 0; u < 32; ++u){ run = run + b0[u]; pbuf[j + u] = run; }
      if (j + 64 < NPTS){
        #pragma unroll
        for (int u = 0; u < 32; ++u) b0[u] = sbuf[j + 64 + u];
      }
      #pragma unroll
      for (int u = 0; u < 32; ++u){ run = run + b1[u]; pbuf[j + 32 + u] = run; }
    }
  }
  __syncthreads();
  int cnt = 0;
  for (int e = tid; e < NPTS; e += NTHR) cnt += (pbuf[e] <= rT) ? 1 : 0;
  #pragma unroll
  for (int o = 32; o; o >>= 1) cnt += __shfl_xor(cnt, o, 64);
  if (l == 0) ired[w] = cnt;
  __syncthreads();
  int sel = (ired[0] + ired[1] + ired[2] + ired[3]) - 1;
  for (int d = tid; d < DIMS; d += NTHR){
    float v = 0.f;
    if (sel >= 0){
      int ns = sel / TLEN, ts = sel - ns*TLEN;
      v = X[((size_t)(bs*NSPK_ + ns)*DIMS + d)*TLEN + ts];
    }
    C[(bs*KC + i)*DIMS + d] = v;
  }
}

// reduce-scatter pair step (identical pairing to the verified v1 kernel)
#define RSTEP(lo_v, hi_v, off, bitset, dst) do {            \
    float snd_ = (bitset) ? (lo_v) : (hi_v);                \
    float kp_  = (bitset) ? (hi_v) : (lo_v);                \
    dst = kp_ + __shfl_xor(snd_, off, 64); } while (0)

// Frozen-batch predicate: C[b] bitwise == Cprev[b] (2048 words). No protocol:
// once true, nobody writes C[b]/Cprev[b] again -> sticky automatically.
// 256 threads x 2 uint4 each covers all 512 uint4.
#define FROZEN_PRED(CB, PB, OKW)  do {                                   \
    const uint4* C4_ = (const uint4*)(CB);                               \
    const uint4* P4_ = (const uint4*)(PB);                               \
    uint4 a0_ = C4_[tid*2],   a1_ = C4_[tid*2+1];                        \
    uint4 p0_ = P4_[tid*2],   p1_ = P4_[tid*2+1];                        \
    bool ok_ = (a0_.x==p0_.x) && (a0_.y==p0_.y) && (a0_.z==p0_.z) &&     \
               (a0_.w==p0_.w) && (a1_.x==p1_.x) && (a1_.y==p1_.y) &&     \
               (a1_.z==p1_.z) && (a1_.w==p1_.w);                         \
    unsigned long long bad_ = __ballot(!ok_);                            \
    if (l == 0) OKW[w] = (bad_ == 0ull) ? 1 : 0;                         \
  } while (0)

// ======== Lloyd iteration v3 (verified bit-exact) + protocol-free per-batch
// fixed-point exit. Batches are independent chains, so C[b]==Cprev[b] bitwise
// implies every later iteration is a no-op for batch b.
__global__ __launch_bounds__(NTHR, 3)
void k_iter(const float* __restrict__ X, const float* __restrict__ C,
            const float* __restrict__ Cprev, const float* __restrict__ fsq,
            float* __restrict__ part, int* __restrict__ pnum){
  const int blk = blockIdx.x, tid = threadIdx.x;
  const int b = blk / BPB;
  const int w = tid >> 6, l = tid & 63;
  const int pq = tid & 3;
  const int dgg = tid >> 2;                 // 0..63 (d-row group)
  const int dl = l >> 2;                    // dgg within wave: 0..15
  const int g0 = (blk - b*BPB)*PPB;

  __shared__ __align__(16) float red2[2][4][4][16]; // 2 KB double-buffered
  __shared__ float csq_s[KC];
  __shared__ int   okw[4];

  const float* Cb = C + b*KC*DIMS;
  FROZEN_PRED(Cb, Cprev + (size_t)b*KC*DIMS, okw);

  // csq (identical to v1: wave w computes cluster w)
  { const float* ck = Cb + w*DIMS + l*8;
    float s = 0.f;
    #pragma unroll
    for (int j = 0; j < 8; ++j){ float c = ck[j]; s += c*c; }
    #pragma unroll
    for (int o = 32; o; o >>= 1) s += __shfl_xor(s, o, 64);
    if (l == 0) csq_s[w] = s * (1.f/512.f);
  }
  __syncthreads();                          // prologue barrier (pred + csq)
  if (okw[0] && okw[1] && okw[2] && okw[3]) return;   // batch b at fixed point

  const float cs0 = csq_s[0], cs1 = csq_s[1], cs2 = csq_s[2], cs3 = csq_s[3];

  // fsq for the redundant-argmin lane (p = l & 15), one per round
  const int pl = l & 15;
  float fq[4];
  #pragma unroll
  for (int h = 0; h < 4; ++h)
    fq[h] = fsq[b*NPTS + g0 + h*16 + pl];

  // center registers: cr[dd] = {C[k=0..3][dd*64+dgg]} (C is L2-hot, 64 KB)
  float4 cr[8];
  #pragma unroll
  for (int dd = 0; dd < 8; ++dd){
    int d = dd*64 + dgg;
    cr[dd].x = Cb[0*DIMS + d];
    cr[dd].y = Cb[1*DIMS + d];
    cr[dd].z = Cb[2*DIMS + d];
    cr[dd].w = Cb[3*DIMS + d];
  }

  // prologue: load round 0's x-quad
  float4 x4[8];
  { const int gp = g0 + pq*4;
    const int n = gp / TLEN, t = gp - n*TLEN;
    const float* xr = X + ((size_t)(b*NSPK_ + n)*DIMS + dgg)*TLEN + t;
    #pragma unroll
    for (int dd = 0; dd < 8; ++dd)
      x4[dd] = *(const float4*)(xr + (size_t)dd*64*TLEN);
  }

  float4 acc[8];
  #pragma unroll
  for (int dd = 0; dd < 8; ++dd) acc[dd] = make_float4(0.f,0.f,0.f,0.f);
  int c0=0, c1=0, c2=0, c3=0;

  const bool hb0 = dl & 1, hb1 = dl & 2, hb2 = dl & 4, hb3 = dl & 8;

  #pragma unroll
  for (int h = 0; h < 4; ++h){
    // prefetch next round's quad FIRST -> latency hides under this round's work
    float4 x4n[8];
    if (h < 3){
      const int gp = g0 + (h+1)*16 + pq*4;  // 2000%4==0 -> quad never straddles n
      const int n = gp / TLEN, t = gp - n*TLEN;
      const float* xr = X + ((size_t)(b*NSPK_ + n)*DIMS + dgg)*TLEN + t;
      #pragma unroll
      for (int dd = 0; dd < 8; ++dd)
        x4n[dd] = *(const float4*)(xr + (size_t)dd*64*TLEN);
    }

    // dots (v1 order, bit-identical)
    float4 a0 = {0,0,0,0}, a1 = {0,0,0,0}, a2 = {0,0,0,0}, a3 = {0,0,0,0};
    #pragma unroll
    for (int dd = 0; dd < 8; ++dd){
      float4 c = cr[dd];
      a0.x += x4[dd].x*c.x; a0.y += x4[dd].x*c.y; a0.z += x4[dd].x*c.z; a0.w += x4[dd].x*c.w;
      a1.x += x4[dd].y*c.x; a1.y += x4[dd].y*c.y; a1.z += x4[dd].y*c.z; a1.w += x4[dd].y*c.w;
      a2.x += x4[dd].z*c.x; a2.y += x4[dd].z*c.y; a2.z += x4[dd].z*c.z; a2.w += x4[dd].z*c.w;
      a3.x += x4[dd].w*c.x; a3.y += x4[dd].w*c.y; a3.z += x4[dd].w*c.z; a3.w += x4[dd].w*c.w;
    }
    // reduce-scatter over the 16 dgg-lanes sharing pq (v1 verbatim: bit-identical)
    float t0,t1,t2,t3,t4,t5,t6,t7;
    RSTEP(a0.x, a0.y, 4, hb0, t0);
    RSTEP(a0.z, a0.w, 4, hb0, t1);
    RSTEP(a1.x, a1.y, 4, hb0, t2);
    RSTEP(a1.z, a1.w, 4, hb0, t3);
    RSTEP(a2.x, a2.y, 4, hb0, t4);
    RSTEP(a2.z, a2.w, 4, hb0, t5);
    RSTEP(a3.x, a3.y, 4, hb0, t6);
    RSTEP(a3.z, a3.w, 4, hb0, t7);
    float u0,u1,u2,u3;
    RSTEP(t0, t1, 8, hb1, u0);
    RSTEP(t2, t3, 8, hb1, u1);
    RSTEP(t4, t5, 8, hb1, u2);
    RSTEP(t6, t7, 8, hb1, u3);
    float v0,v1;
    RSTEP(u0, u1, 16, hb2, v0);
    RSTEP(u2, u3, 16, hb2, v1);
    float rr;
    RSTEP(v0, v1, 32, hb3, rr);
    red2[h&1][w][pq][dl] = rr;
    __syncthreads();                        // the ONLY barrier per round

    // redundant all-wave argmin (p = l&15; combine order identical to v1)
    {
      const int pqq = pl >> 2, jj = pl & 3;
      float4 A = {0,0,0,0};
      #pragma unroll
      for (int q = 0; q < 4; ++q){
        float4 v = ((const float4*)&red2[h&1][q][pqq][0])[jj];
        A.x += v.x; A.y += v.y; A.z += v.z; A.w += v.w;
      }
      float xs = fq[h] * (1.f/512.f);
      float e0 = (xs + cs0) - 2.f*(A.x*(1.f/512.f));
      float e1 = (xs + cs1) - 2.f*(A.y*(1.f/512.f));
      float e2 = (xs + cs2) - 2.f*(A.z*(1.f/512.f));
      float e3 = (xs + cs3) - 2.f*(A.w*(1.f/512.f));
      int bi = 0; float bv = e0;            // first-min == np.argmin
      if (e1 < bv){ bv = e1; bi = 1; }
      if (e2 < bv){ bv = e2; bi = 2; }
      if (e3 < bv){ bv = e3; bi = 3; }
      unsigned long long m0 = __ballot(bi==0), m1 = __ballot(bi==1);
      unsigned long long m2 = __ballot(bi==2), m3 = __ballot(bi==3);
      c0 += __popcll(m0 & 0xFFFFull); c1 += __popcll(m1 & 0xFFFFull);
      c2 += __popcll(m2 & 0xFFFFull); c3 += __popcll(m3 & 0xFFFFull);

      // cluster sums for MY 4 points (pq*4+j): masks from ballot bits,
      // register FMAs on the x4 already held -- no LDS tile.
      #pragma unroll
      for (int j = 0; j < 4; ++j){
        const int pj = pq*4 + j;
        float f0 = (float)((m0 >> pj) & 1ull);
        float f1 = (float)((m1 >> pj) & 1ull);
        float f2 = (float)((m2 >> pj) & 1ull);
        float f3 = (float)((m3 >> pj) & 1ull);
        #pragma unroll
        for (int dd = 0; dd < 8; ++dd){
          float xv = (j==0) ? x4[dd].x : (j==1) ? x4[dd].y : (j==2) ? x4[dd].z : x4[dd].w;
          acc[dd].x += xv*f0; acc[dd].y += xv*f1; acc[dd].z += xv*f2; acc[dd].w += xv*f3;
        }
      }
    }
    // rotate buffers (register rename under full unroll)
    if (h < 3){
      #pragma unroll
      for (int dd = 0; dd < 8; ++dd) x4[dd] = x4n[dd];
    }
  }

  // epilogue: reduce acc over the 4 pq lanes sharing each d (tree (0+1)+(2+3))
  #pragma unroll
  for (int dd = 0; dd < 8; ++dd){
    acc[dd].x += __shfl_xor(acc[dd].x, 1, 64);
    acc[dd].y += __shfl_xor(acc[dd].y, 1, 64);
    acc[dd].z += __shfl_xor(acc[dd].z, 1, 64);
    acc[dd].w += __shfl_xor(acc[dd].w, 1, 64);
    acc[dd].x += __shfl_xor(acc[dd].x, 2, 64);
    acc[dd].y += __shfl_xor(acc[dd].y, 2, 64);
    acc[dd].z += __shfl_xor(acc[dd].z, 2, 64);
    acc[dd].w += __shfl_xor(acc[dd].w, 2, 64);
  }
  // store part[blk][d][k]: lane (dgg,pq) writes component pq at d=dd*64+dgg
  float* pb = part + (size_t)blk*DIMS*KC;
  #pragma unroll
  for (int dd = 0; dd < 8; ++dd){
    float v = (pq==0) ? acc[dd].x : (pq==1) ? acc[dd].y : (pq==2) ? acc[dd].z : acc[dd].w;
    pb[dd*256 + tid] = v;
  }
  if (tid == 0){
    int4 c4 = {c0, c1, c2, c3};
    *(int4*)&pnum[blk*4] = c4;              // counts identical in every lane
  }
}

// ======== reduce partials -> centers. grid RBLK=64: blk = bb*8 + seg(64 d's)
// Same frozen predicate as k_iter (deterministic, same state -> same answer).
// Active path: save old C into Cprev, then overwrite C with new centers.
__global__ __launch_bounds__(NTHR)
void k_reduce(const float* __restrict__ part, const int* __restrict__ pnum,
              float* __restrict__ C, float* __restrict__ Cprev){
  const int blk = blockIdx.x, tid = threadIdx.x;
  const int seg = blk & 7, bb = blk >> 3;
  const int w = tid >> 6, l = tid & 63;
  __shared__ __align__(16) float4 red[4][64];
  __shared__ int4 nsw[4];
  __shared__ int okw[4];

  FROZEN_PRED(C + bb*KC*DIMS, Cprev + (size_t)bb*KC*DIMS, okw);
  __syncthreads();
  if (okw[0] && okw[1] && okw[2] && okw[3]) return;   // batch bb frozen

  int4 v = {0,0,0,0};
  if (tid < BPB) v = *(const int4*)&pnum[(bb*BPB + tid)*4];
  #pragma unroll
  for (int o = 32; o; o >>= 1){
    v.x += __shfl_xor(v.x, o, 64); v.y += __shfl_xor(v.y, o, 64);
    v.z += __shfl_xor(v.z, o, 64); v.w += __shfl_xor(v.w, o, 64);
  }
  if (l == 0) nsw[w] = v;

  int jb = (BPB*w) >> 2, je = (BPB*(w+1)) >> 2;   // fixed quarters of 125
  float4 s = {0,0,0,0};
  const float4* pp = (const float4*)part;
  for (int j = jb; j < je; ++j){
    float4 t = pp[(size_t)(bb*BPB + j)*DIMS + seg*64 + l];
    s.x += t.x; s.y += t.y; s.z += t.z; s.w += t.w;
  }
  red[w][l] = s;
  __syncthreads();
  if (tid < 64){
    float4 r0 = red[0][l], r1 = red[1][l], r2 = red[2][l], r3 = red[3][l];
    float tsx = r0.x + r1.x + r2.x + r3.x;
    float tsy = r0.y + r1.y + r2.y + r3.y;
    float tsz = r0.z + r1.z + r2.z + r3.z;
    float tsw = r0.w + r1.w + r2.w + r3.w;
    int4 n0 = nsw[0], n1 = nsw[1], n2 = nsw[2], n3 = nsw[3];
    float dx = (float)(n0.x+n1.x+n2.x+n3.x) + 1e-8f;
    float dy = (float)(n0.y+n1.y+n2.y+n3.y) + 1e-8f;
    float dz = (float)(n0.z+n1.z+n2.z+n3.z) + 1e-8f;
    float dw = (float)(n0.w+n1.w+n2.w+n3.w) + 1e-8f;
    float nx = tsx / dx, ny = tsy / dy, nz = tsz / dz, nw2 = tsw / dw;
    float* Cp = C + bb*KC*DIMS + seg*64 + l;
    float* Pp = Cprev + (size_t)bb*KC*DIMS + seg*64 + l;
    // save old centers to Cprev, then overwrite C (fixed-point test next iter)
    Pp[0]        = Cp[0];
    Pp[DIMS]     = Cp[DIMS];
    Pp[2*DIMS]   = Cp[2*DIMS];
    Pp[3*DIMS]   = Cp[3*DIMS];
    Cp[0]        = nx;
    Cp[DIMS]     = ny;
    Cp[2*DIMS]   = nz;
    Cp[3*DIMS]   = nw2;
  }
}

// ======================= host: threefry2x32 (JAX-compatible) =======================
static inline uint32_t rotl_(uint32_t x, int r){ return (x << r) | (x >> (32 - r)); }
static void tf2x32(uint32_t k0, uint32_t k1, uint32_t x0, uint32_t x1,
                   uint32_t* o0, uint32_t* o1){
  static const int R0[4] = {13,15,26,6}, R1[4] = {17,29,16,24};
  uint32_t ks[3] = { k0, k1, k0 ^ k1 ^ 0x1BD11BDAu };
  x0 += ks[0]; x1 += ks[1];
  for (int g = 0; g < 5; ++g){
    const int* rot = (g & 1) ? R1 : R0;
    for (int r = 0; r < 4; ++r){ x0 += x1; x1 = rotl_(x1, rot[r]); x1 ^= x0; }
    x0 += ks[(g+1)%3];
    x1 += ks[(g+2)%3] + (uint32_t)(g+1);
  }
  *o0 = x0; *o1 = x1;
}
static float tf_uniform_bits(uint32_t bits){
  uint32_t u = (bits >> 9) | 0x3f800000u;
  float f; memcpy(&f, &u, 4);
  return f - 1.0f;
}

extern "C" void kernel_launch(void* const* d_in, const int* in_sizes, int n_in,
                              void* d_out, int out_size, void* d_ws, size_t ws_size,
                              hipStream_t stream) {
  (void)in_sizes; (void)n_in; (void)out_size; (void)ws_size;
  const float* X = (const float*)d_in[0];
  float* centers = (float*)d_out;                 // (8,4,512)

  char* w = (char*)d_ws;
  float* fsq   = (float*)w;  w += (size_t)NBATCH*NPTS*4;            // 256 KB
  float* dmin  = (float*)w;  w += (size_t)NBATCH*NPTS*4;            // 256 KB
  float* part  = (float*)w;  w += (size_t)NBLK*DIMS*KC*4;           // 8.2 MB [blk][d][k]
  int*   pnum  = (int*)w;    w += (size_t)NBLK*KC*4;                // 16 KB
  float* cprev = (float*)w;  w += (size_t)NBATCH*KC*DIMS*4;         // 64 KB

  RArg ra;
  uint32_t k0 = 0u, k1 = 1u;
  for (int i = 0; i < 3; ++i){
#if THREEFRY_PARTITIONABLE
    uint32_t nk0, nk1, s0, s1;
    tf2x32(k0, k1, 0u, 0u, &nk0, &nk1);
    tf2x32(k0, k1, 0u, 1u, &s0, &s1);
    k0 = nk0; k1 = nk1;
    for (int bq = 0; bq < NBATCH; ++bq){
      uint32_t b1v, b2v; tf2x32(s0, s1, 0u, (uint32_t)bq, &b1v, &b2v);
      ra.r[i][bq] = tf_uniform_bits(b1v ^ b2v);
    }
#else
    uint32_t a0, b0, a1, b1;
    tf2x32(k0, k1, 0u, 2u, &a0, &b0);
    tf2x32(k0, k1, 1u, 3u, &a1, &b1);
    uint32_t s0 = b0, s1 = b1;
    k0 = a0; k1 = a1;
    uint32_t bits[8];
    for (int j = 0; j < 4; ++j){
      uint32_t c, d2; tf2x32(s0, s1, (uint32_t)j, (uint32_t)(j+4), &c, &d2);
      bits[j] = c; bits[j+4] = d2;
    }
    for (int bq = 0; bq < NBATCH; ++bq) ra.r[i][bq] = tf_uniform_bits(bits[bq]);
#endif
  }

  hipLaunchKernelGGL(k_prep, dim3(NBLK), dim3(NTHR), 0, stream, X, centers, cprev, fsq);
  for (int i = 1; i < KC; ++i){
    hipLaunchKernelGGL(k_dist, dim3(NBLK), dim3(NTHR), 0, stream, X, centers, fsq, dmin);
    hipLaunchKernelGGL(k_select, dim3(NBATCH), dim3(NTHR), 0, stream, X, centers, dmin, ra, i);
  }
  for (int it = 0; it < MAXIT; ++it){
    hipLaunchKernelGGL(k_iter, dim3(NBLK), dim3(NTHR), 0, stream, X, centers, cprev, fsq, part, pnum);
    hipLaunchKernelGGL(k_reduce, dim3(RBLK), dim3(NTHR), 0, stream, part, pnum, centers, cprev);
  }
}